// Round 2
// baseline (5958.745 us; speedup 1.0000x reference)
//
#include <hip/hip_runtime.h>
#include <hip/hip_bf16.h>

// BERT stack: L=12(+1 dup of layer0), H=12, E=768, D=64, B=4, S=512 -> BS=2048 tokens.
// Faithful bugs preserved:
//  - attention flattens batch: 2048 tokens attend to each other globally, q==k==v
//  - zc = z.reshape(768,2048) is a FLAT VIEW of z[H][N][D]  (no transpose)
//  - mh = (wo@zc).reshape(B,S,E) is a FLAT VIEW of mh_mat[768][2048]
//  - pe: p = 10000 for e<384 else 10001; even e -> sin, odd -> cos; s = t % 512
// All inputs/outputs fp32 (per reference dtypes); compute fp32.

#define BS_TOK 2048
#define EMB 768
#define NH 12
#define HD 64

// ---------------------------------------------------------------- pe + tokens
__global__ __launch_bounds__(256) void pe_add_kernel(const float* __restrict__ tok,
                                                     float* __restrict__ X) {
  int idx = blockIdx.x * 256 + threadIdx.x;   // < 2048*768
  int e = idx % EMB;
  int t = idx / EMB;
  int s = t & 511;                            // t = b*512 + s
  float p = (e < 384) ? 10000.0f : 10001.0f;  // 10000 XOR ((2e)//768)
  float ang = (float)s / p;
  float pe = (e & 1) ? cosf(ang) : sinf(ang);
  X[idx] = tok[idx] + pe;
}

#define FMA44(acc, a4, b4)                                   \
  {                                                          \
    float a_[4] = {a4.x, a4.y, a4.z, a4.w};                  \
    float b_[4] = {b4.x, b4.y, b4.z, b4.w};                  \
    _Pragma("unroll") for (int i_ = 0; i_ < 4; ++i_)         \
        _Pragma("unroll") for (int j_ = 0; j_ < 4; ++j_)     \
            acc[i_][j_] = fmaf(a_[i_], b_[j_], acc[i_][j_]); \
  }

// ------------------------------------------------- Q = X[2048x768] * Wq -> [H][N][D]
__global__ __launch_bounds__(256) void gemm_q_kernel(const float* __restrict__ X,
                                                     const float* __restrict__ Wq,
                                                     float* __restrict__ Qo) {
  __shared__ float As[16][68];
  __shared__ float Bs[16][68];
  const int m0 = blockIdx.x * 64;   // token tile
  const int h = blockIdx.y;         // head == N-tile (BN=64=D)
  const int tid = threadIdx.x;
  const int tx = tid & 15, ty = tid >> 4;
  const int arow = tid >> 2, ak4 = (tid & 3) << 2;
  const int bn = tid & 63, bk0 = (tid >> 6) << 2;
  const float* wqh = Wq + h * (EMB * HD);
  float acc[4][4] = {};
  for (int k0 = 0; k0 < EMB; k0 += 16) {
    float4 av = *(const float4*)(X + (m0 + arow) * EMB + k0 + ak4);
    As[ak4 + 0][arow] = av.x;
    As[ak4 + 1][arow] = av.y;
    As[ak4 + 2][arow] = av.z;
    As[ak4 + 3][arow] = av.w;
#pragma unroll
    for (int j = 0; j < 4; ++j)
      Bs[bk0 + j][bn] = wqh[(k0 + bk0 + j) * HD + bn];
    __syncthreads();
#pragma unroll
    for (int kk = 0; kk < 16; ++kk) {
      float4 a4 = *(const float4*)&As[kk][ty << 2];
      float4 b4 = *(const float4*)&Bs[kk][tx << 2];
      FMA44(acc, a4, b4);
    }
    __syncthreads();
  }
#pragma unroll
  for (int i = 0; i < 4; ++i) {
    float4 ov = make_float4(acc[i][0], acc[i][1], acc[i][2], acc[i][3]);
    *(float4*)(Qo + h * (BS_TOK * HD) + (m0 + (ty << 2) + i) * HD + (tx << 2)) = ov;
  }
}

// ------------------------------------------------- flash attention, q==k==v, 2048 keys
__global__ __launch_bounds__(256) void attn_kernel(const float* __restrict__ Q,
                                                   float* __restrict__ Z) {
  __shared__ float Qs[64][68];    // [d][row]   (Q tile transposed)
  __shared__ float KtPs[64][68];  // [d][key] for S, then reused as P[key][row]
  __shared__ float Kr[64][68];    // [key][d]  (V tile)
  const int h = blockIdx.y;
  const int q0 = blockIdx.x * 64;
  const int tid = threadIdx.x;
  const int tx = tid & 15, ty = tid >> 4;
  const float* Qh = Q + h * (BS_TOK * HD);
  {  // load Q tile transposed
    const int f4 = tid & 15;
    const int r0 = tid >> 4;
#pragma unroll
    for (int p = 0; p < 4; ++p) {
      int row = r0 + p * 16;
      float4 v = *(const float4*)(Qh + (q0 + row) * HD + (f4 << 2));
      Qs[(f4 << 2) + 0][row] = v.x;
      Qs[(f4 << 2) + 1][row] = v.y;
      Qs[(f4 << 2) + 2][row] = v.z;
      Qs[(f4 << 2) + 3][row] = v.w;
    }
  }
  float o[4][4] = {};
  float mi[4], li[4];
#pragma unroll
  for (int i = 0; i < 4; ++i) {
    mi[i] = -1e30f;
    li[i] = 0.f;
  }
  for (int kt = 0; kt < 32; ++kt) {
    __syncthreads();  // previous PV (reads Kr, KtPs) done
    {                 // load K tile: raw into Kr, transposed into KtPs
      const int f4 = tid & 15;
      const int r0 = tid >> 4;
#pragma unroll
      for (int p = 0; p < 4; ++p) {
        int row = r0 + p * 16;
        float4 v = *(const float4*)(Qh + (kt * 64 + row) * HD + (f4 << 2));
        *(float4*)&Kr[row][f4 << 2] = v;
        KtPs[(f4 << 2) + 0][row] = v.x;
        KtPs[(f4 << 2) + 1][row] = v.y;
        KtPs[(f4 << 2) + 2][row] = v.z;
        KtPs[(f4 << 2) + 3][row] = v.w;
      }
    }
    __syncthreads();
    float s[4][4] = {};
#pragma unroll 8
    for (int kk = 0; kk < 64; ++kk) {
      float4 a4 = *(const float4*)&Qs[kk][ty << 2];
      float4 b4 = *(const float4*)&KtPs[kk][tx << 2];
      FMA44(s, a4, b4);
    }
    float pv[4][4];
#pragma unroll
    for (int i = 0; i < 4; ++i) {
#pragma unroll
      for (int j = 0; j < 4; ++j) s[i][j] *= 0.125f;  // / sqrt(64)
      float tm = fmaxf(fmaxf(s[i][0], s[i][1]), fmaxf(s[i][2], s[i][3]));
#pragma unroll
      for (int d = 1; d < 16; d <<= 1) tm = fmaxf(tm, __shfl_xor(tm, d, 64));
      float nm = fmaxf(mi[i], tm);
      float alpha = __expf(mi[i] - nm);
      mi[i] = nm;
      float rs = 0.f;
#pragma unroll
      for (int j = 0; j < 4; ++j) {
        pv[i][j] = __expf(s[i][j] - nm);
        rs += pv[i][j];
      }
#pragma unroll
      for (int d = 1; d < 16; d <<= 1) rs += __shfl_xor(rs, d, 64);
      li[i] = li[i] * alpha + rs;
#pragma unroll
      for (int j = 0; j < 4; ++j) o[i][j] *= alpha;
    }
    __syncthreads();  // all lanes done reading KtPs as K^T
#pragma unroll
    for (int i = 0; i < 4; ++i)
#pragma unroll
      for (int j = 0; j < 4; ++j) KtPs[(tx << 2) + j][(ty << 2) + i] = pv[i][j];
    __syncthreads();  // P visible
#pragma unroll 8
    for (int kk = 0; kk < 64; ++kk) {
      float4 p4 = *(const float4*)&KtPs[kk][ty << 2];
      float4 v4 = *(const float4*)&Kr[kk][tx << 2];
      FMA44(o, p4, v4);
    }
  }
#pragma unroll
  for (int i = 0; i < 4; ++i) {
    float inv = 1.0f / li[i];
    float4 ov = make_float4(o[i][0] * inv, o[i][1] * inv, o[i][2] * inv, o[i][3] * inv);
    *(float4*)(Z + h * (BS_TOK * HD) + (q0 + (ty << 2) + i) * HD + (tx << 2)) = ov;
  }
}

// ------------------------------------------------- MH = Wo[768x768] * Zflat[768x2048]
__global__ __launch_bounds__(256) void gemm_out_kernel(const float* __restrict__ Wo,
                                                       const float* __restrict__ Zc,
                                                       float* __restrict__ MH) {
  __shared__ float As[16][68];
  __shared__ float Bs[16][68];
  const int n0 = blockIdx.x * 64;  // j cols (2048 -> 32 tiles)
  const int m0 = blockIdx.y * 64;  // e rows (768 -> 12 tiles)
  const int tid = threadIdx.x;
  const int tx = tid & 15, ty = tid >> 4;
  const int arow = tid >> 2, ak4 = (tid & 3) << 2;
  const int bn = tid & 63, bk0 = (tid >> 6) << 2;
  float acc[4][4] = {};
  for (int k0 = 0; k0 < EMB; k0 += 16) {
    float4 av = *(const float4*)(Wo + (m0 + arow) * EMB + k0 + ak4);
    As[ak4 + 0][arow] = av.x;
    As[ak4 + 1][arow] = av.y;
    As[ak4 + 2][arow] = av.z;
    As[ak4 + 3][arow] = av.w;
#pragma unroll
    for (int j = 0; j < 4; ++j)
      Bs[bk0 + j][bn] = Zc[(k0 + bk0 + j) * BS_TOK + n0 + bn];
    __syncthreads();
#pragma unroll
    for (int kk = 0; kk < 16; ++kk) {
      float4 a4 = *(const float4*)&As[kk][ty << 2];
      float4 b4 = *(const float4*)&Bs[kk][tx << 2];
      FMA44(acc, a4, b4);
    }
    __syncthreads();
  }
#pragma unroll
  for (int i = 0; i < 4; ++i) {
    float4 ov = make_float4(acc[i][0], acc[i][1], acc[i][2], acc[i][3]);
    *(float4*)(MH + (m0 + (ty << 2) + i) * BS_TOK + n0 + (tx << 2)) = ov;
  }
}

// ------------------------------------------------- FFN = L1[2048x768] * fw^T + fb
__global__ __launch_bounds__(256) void gemm_ffn_kernel(const float* __restrict__ L1,
                                                       const float* __restrict__ Fw,
                                                       const float* __restrict__ Fb,
                                                       float* __restrict__ Out) {
  __shared__ float As[16][68];
  __shared__ float Bs[16][68];
  const int m0 = blockIdx.x * 64;  // token tile (32)
  const int n0 = blockIdx.y * 64;  // out-feature tile (12)
  const int tid = threadIdx.x;
  const int tx = tid & 15, ty = tid >> 4;
  const int arow = tid >> 2, ak4 = (tid & 3) << 2;
  const int bn = tid & 63, bk0 = (tid >> 6) << 2;
  float acc[4][4] = {};
  for (int k0 = 0; k0 < EMB; k0 += 16) {
    float4 av = *(const float4*)(L1 + (m0 + arow) * EMB + k0 + ak4);
    As[ak4 + 0][arow] = av.x;
    As[ak4 + 1][arow] = av.y;
    As[ak4 + 2][arow] = av.z;
    As[ak4 + 3][arow] = av.w;
    {  // fw[o][k]: contiguous in k for fixed o=n0+bn
      float4 bv = *(const float4*)(Fw + (n0 + bn) * EMB + k0 + bk0);
      Bs[bk0 + 0][bn] = bv.x;
      Bs[bk0 + 1][bn] = bv.y;
      Bs[bk0 + 2][bn] = bv.z;
      Bs[bk0 + 3][bn] = bv.w;
    }
    __syncthreads();
#pragma unroll
    for (int kk = 0; kk < 16; ++kk) {
      float4 a4 = *(const float4*)&As[kk][ty << 2];
      float4 b4 = *(const float4*)&Bs[kk][tx << 2];
      FMA44(acc, a4, b4);
    }
    __syncthreads();
  }
#pragma unroll
  for (int i = 0; i < 4; ++i) {
    float4 ov;
    ov.x = acc[i][0] + Fb[n0 + (tx << 2) + 0];
    ov.y = acc[i][1] + Fb[n0 + (tx << 2) + 1];
    ov.z = acc[i][2] + Fb[n0 + (tx << 2) + 2];
    ov.w = acc[i][3] + Fb[n0 + (tx << 2) + 3];
    *(float4*)(Out + (m0 + (ty << 2) + i) * EMB + n0 + (tx << 2)) = ov;
  }
}

// ------------------------------------------------- LN(Xa + Xb) row-wise over 768
__global__ __launch_bounds__(256) void ln_kernel(const float* __restrict__ Xa,
                                                 const float* __restrict__ Xb,
                                                 const float* __restrict__ g,
                                                 const float* __restrict__ bb,
                                                 float* __restrict__ Out) {
  __shared__ float red[4];
  const int t = blockIdx.x;
  const int tid = threadIdx.x;
  float v[3];
  float s = 0.f;
#pragma unroll
  for (int i = 0; i < 3; ++i) {
    int e = tid + i * 256;
    v[i] = Xa[t * EMB + e] + Xb[t * EMB + e];
    s += v[i];
  }
#pragma unroll
  for (int o = 32; o > 0; o >>= 1) s += __shfl_xor(s, o, 64);
  if ((tid & 63) == 0) red[tid >> 6] = s;
  __syncthreads();
  float mu = (red[0] + red[1] + red[2] + red[3]) * (1.0f / EMB);
  float q = 0.f;
#pragma unroll
  for (int i = 0; i < 3; ++i) {
    float d = v[i] - mu;
    q += d * d;
  }
#pragma unroll
  for (int o = 32; o > 0; o >>= 1) q += __shfl_xor(q, o, 64);
  __syncthreads();  // done reading red
  if ((tid & 63) == 0) red[tid >> 6] = q;
  __syncthreads();
  float var = (red[0] + red[1] + red[2] + red[3]) * (1.0f / EMB);
  float r = rsqrtf(var + 1e-5f);
#pragma unroll
  for (int i = 0; i < 3; ++i) {
    int e = tid + i * 256;
    Out[t * EMB + e] = (v[i] - mu) * r * g[e] + bb[e];
  }
}

extern "C" void kernel_launch(void* const* d_in, const int* in_sizes, int n_in,
                              void* d_out, int out_size, void* d_ws, size_t ws_size,
                              hipStream_t stream) {
  const float* tok = (const float*)d_in[0];
  const float* wq = (const float*)d_in[1];
  const float* wo = (const float*)d_in[2];
  const float* g1 = (const float*)d_in[3];
  const float* b1 = (const float*)d_in[4];
  const float* fw = (const float*)d_in[5];
  const float* fb = (const float*)d_in[6];
  const float* g2 = (const float*)d_in[7];
  const float* b2 = (const float*)d_in[8];
  const int NB = BS_TOK * EMB;  // 1572864 elems per activation buffer
  float* X = (float*)d_ws;
  float* Qb = X + NB;
  float* Zb = X + 2 * NB;

  pe_add_kernel<<<NB / 256, 256, 0, stream>>>(tok, X);
  for (int it = 0; it < 13; ++it) {
    int l = (it == 0) ? 0 : it - 1;  // layer 0 applied twice (faithful)
    const float* wql = wq + (size_t)l * (NH * EMB * HD);
    const float* wol = wo + (size_t)l * (EMB * NH * HD);
    const float* fwl = fw + (size_t)l * (EMB * EMB);
    gemm_q_kernel<<<dim3(32, 12), 256, 0, stream>>>(X, wql, Qb);
    attn_kernel<<<dim3(32, 12), 256, 0, stream>>>(Qb, Zb);
    gemm_out_kernel<<<dim3(32, 12), 256, 0, stream>>>(wol, Zb, Qb);    // MH -> Qb
    ln_kernel<<<BS_TOK, 256, 0, stream>>>(X, Qb, g1 + l * EMB, b1 + l * EMB, Zb);  // L1 -> Zb
    gemm_ffn_kernel<<<dim3(32, 12), 256, 0, stream>>>(Zb, fwl, fb + l * EMB, X);   // FFN -> X
    float* ln2_dst = (it == 12) ? (float*)d_out : Qb;
    ln_kernel<<<BS_TOK, 256, 0, stream>>>(Zb, X, g2 + l * EMB, b2 + l * EMB, ln2_dst);
    float* tmp = X;
    X = Qb;
    Qb = tmp;
  }
}

// Round 3
// 3422.445 us; speedup vs baseline: 1.7411x; 1.7411x over previous
//
#include <hip/hip_runtime.h>
#include <hip/hip_bf16.h>

// BERT stack: L=12(+1 dup of layer0), H=12, E=768, D=64, B=4, S=512 -> BS=2048 tokens.
// Faithful bugs preserved:
//  - attention flattens batch: 2048 tokens attend to each other globally, q==k==v
//  - zc = z.reshape(768,2048) is a FLAT VIEW of z[H][N][D]  (no transpose)
//  - mh = (wo@zc).reshape(B,S,E) is a FLAT VIEW of mh_mat[768][2048]
//  - pe: p = 10000 for e<384 else 10001; even e -> sin, odd -> cos; s = t % 512
// Inputs/outputs fp32. GEMMs fp32; attention uses bf16 MFMA (fp32 accumulate).

#define BS_TOK 2048
#define EMB 768
#define NH 12
#define HD 64

typedef __attribute__((ext_vector_type(8))) short bf16x8;
typedef __attribute__((ext_vector_type(4))) float f32x4;

__device__ __forceinline__ short f2bf(float f) {
  union { float f; unsigned u; } v;
  v.f = f;
  unsigned r = (v.u + 0x7FFF + ((v.u >> 16) & 1)) >> 16;  // RNE
  return (short)(unsigned short)r;
}

#define MFMA16(a, b, c) __builtin_amdgcn_mfma_f32_16x16x32_bf16(a, b, c, 0, 0, 0)

// ---------------------------------------------------------------- pe + tokens
__global__ __launch_bounds__(256) void pe_add_kernel(const float* __restrict__ tok,
                                                     float* __restrict__ X) {
  int idx = blockIdx.x * 256 + threadIdx.x;   // < 2048*768
  int e = idx % EMB;
  int t = idx / EMB;
  int s = t & 511;                            // t = b*512 + s
  float p = (e < 384) ? 10000.0f : 10001.0f;  // 10000 XOR ((2e)//768)
  float ang = (float)s / p;
  float pe = (e & 1) ? cosf(ang) : sinf(ang);
  X[idx] = tok[idx] + pe;
}

#define FMA44(acc, a4, b4)                                   \
  {                                                          \
    float a_[4] = {a4.x, a4.y, a4.z, a4.w};                  \
    float b_[4] = {b4.x, b4.y, b4.z, b4.w};                  \
    _Pragma("unroll") for (int i_ = 0; i_ < 4; ++i_)         \
        _Pragma("unroll") for (int j_ = 0; j_ < 4; ++j_)     \
            acc[i_][j_] = fmaf(a_[i_], b_[j_], acc[i_][j_]); \
  }

// ------------------------------------------------- Q = X[2048x768] * Wq -> [H][N][D]
__global__ __launch_bounds__(256) void gemm_q_kernel(const float* __restrict__ X,
                                                     const float* __restrict__ Wq,
                                                     float* __restrict__ Qo) {
  __shared__ float As[16][68];
  __shared__ float Bs[16][68];
  const int m0 = blockIdx.x * 64;   // token tile
  const int h = blockIdx.y;         // head == N-tile (BN=64=D)
  const int tid = threadIdx.x;
  const int tx = tid & 15, ty = tid >> 4;
  const int arow = tid >> 2, ak4 = (tid & 3) << 2;
  const int bn = tid & 63, bk0 = (tid >> 6) << 2;
  const float* wqh = Wq + h * (EMB * HD);
  float acc[4][4] = {};
  for (int k0 = 0; k0 < EMB; k0 += 16) {
    float4 av = *(const float4*)(X + (m0 + arow) * EMB + k0 + ak4);
    As[ak4 + 0][arow] = av.x;
    As[ak4 + 1][arow] = av.y;
    As[ak4 + 2][arow] = av.z;
    As[ak4 + 3][arow] = av.w;
#pragma unroll
    for (int j = 0; j < 4; ++j)
      Bs[bk0 + j][bn] = wqh[(k0 + bk0 + j) * HD + bn];
    __syncthreads();
#pragma unroll
    for (int kk = 0; kk < 16; ++kk) {
      float4 a4 = *(const float4*)&As[kk][ty << 2];
      float4 b4 = *(const float4*)&Bs[kk][tx << 2];
      FMA44(acc, a4, b4);
    }
    __syncthreads();
  }
#pragma unroll
  for (int i = 0; i < 4; ++i) {
    float4 ov = make_float4(acc[i][0], acc[i][1], acc[i][2], acc[i][3]);
    *(float4*)(Qo + h * (BS_TOK * HD) + (m0 + (ty << 2) + i) * HD + (tx << 2)) = ov;
  }
}

// ------------------------------------------------- flash attention, bf16 MFMA
// q==k==v, 2048 keys global. Block = 128 thr (2 waves), Q-tile 32 (16 rows/wave),
// K-tile 64. LDS bf16 tiles XOR-swizzled: element (row,col) stored at
// row*64 + ((col>>3 ^ (row&7))<<3) + (col&7)  -> b128 rows stay 16B aligned,
// bank-balanced frag reads.
__global__ __launch_bounds__(128) void attn_mfma_kernel(const float* __restrict__ Q,
                                                        float* __restrict__ Z) {
  __shared__ short Ks[64 * 64];       // K[key][d]
  __shared__ short Vt[64 * 64];       // V^T[d][key]
  __shared__ short Pw[2 * 16 * 64];   // per-wave P[qrow][key]
  const int h = blockIdx.y;
  const int q0 = blockIdx.x * 32;
  const int tid = threadIdx.x;
  const int lane = tid & 63;
  const int wv = tid >> 6;
  const int l15 = lane & 15;
  const int quad = lane >> 4;
  const float* Qh = Q + h * (BS_TOK * HD);
  short* myP = Pw + wv * 16 * 64;

  // Q A-fragments: A[m=l15][k=kstep*32+quad*8+j], rows q0+wv*16+l15
  bf16x8 qf[2];
  {
    const float* qp = Qh + (q0 + wv * 16 + l15) * HD + quad * 8;
#pragma unroll
    for (int ks = 0; ks < 2; ++ks) {
      float4 x0 = *(const float4*)(qp + ks * 32);
      float4 x1 = *(const float4*)(qp + ks * 32 + 4);
      bf16x8 t;
      t[0] = f2bf(x0.x); t[1] = f2bf(x0.y); t[2] = f2bf(x0.z); t[3] = f2bf(x0.w);
      t[4] = f2bf(x1.x); t[5] = f2bf(x1.y); t[6] = f2bf(x1.z); t[7] = f2bf(x1.w);
      qf[ks] = t;
    }
  }

  f32x4 o[4];
  float m[4], l[4];
#pragma unroll
  for (int r = 0; r < 4; ++r) {
    o[r] = (f32x4){0.f, 0.f, 0.f, 0.f};
    m[r] = -1e30f;
    l[r] = 0.f;
  }

  for (int kt = 0; kt < 32; ++kt) {
    __syncthreads();  // previous iteration's compute done
    {                 // stage K tile: wave wv covers d = wv*32..wv*32+31, key = lane
      const float* src = Qh + (kt * 64 + lane) * HD + wv * 32;
      bf16x8 t4[4];
#pragma unroll
      for (int i = 0; i < 4; ++i) {
        float4 x0 = *(const float4*)(src + i * 8);
        float4 x1 = *(const float4*)(src + i * 8 + 4);
        bf16x8 t;
        t[0] = f2bf(x0.x); t[1] = f2bf(x0.y); t[2] = f2bf(x0.z); t[3] = f2bf(x0.w);
        t[4] = f2bf(x1.x); t[5] = f2bf(x1.y); t[6] = f2bf(x1.z); t[7] = f2bf(x1.w);
        t4[i] = t;
      }
#pragma unroll
      for (int i = 0; i < 4; ++i) {  // Ks[key=lane][d group c] b128, bank-balanced
        int c = wv * 4 + i;
        *(bf16x8*)(&Ks[lane * 64 + ((c ^ (lane & 7)) << 3)]) = t4[i];
      }
#pragma unroll
      for (int j = 0; j < 32; ++j) {  // Vt[d][key=lane] scalar, conflict-free
        int d = wv * 32 + j;
        Vt[d * 64 + (((lane >> 3) ^ (d & 7)) << 3) + (lane & 7)] = t4[j >> 3][j & 7];
      }
    }
    __syncthreads();

    // S = Q K^T / 8  (4 col-tiles of 16 keys)
    f32x4 s[4];
#pragma unroll
    for (int ct = 0; ct < 4; ++ct) {
      f32x4 acc = (f32x4){0.f, 0.f, 0.f, 0.f};
#pragma unroll
      for (int ks = 0; ks < 2; ++ks) {
        int row = ct * 16 + l15;
        int c = ks * 4 + quad;
        bf16x8 kf = *(const bf16x8*)(&Ks[row * 64 + ((c ^ (row & 7)) << 3)]);
        acc = MFMA16(qf[ks], kf, acc);
      }
      s[ct] = acc;
    }

    // online softmax: lane owns rows quad*4+r, col l15 within each col-tile
    float pr[4][4];
#pragma unroll
    for (int r = 0; r < 4; ++r) {
      float tm = -1e30f;
#pragma unroll
      for (int ct = 0; ct < 4; ++ct) {
        s[ct][r] *= 0.125f;
        tm = fmaxf(tm, s[ct][r]);
      }
#pragma unroll
      for (int d = 1; d < 16; d <<= 1) tm = fmaxf(tm, __shfl_xor(tm, d, 64));
      float nm = fmaxf(m[r], tm);
      float alpha = __expf(m[r] - nm);
      m[r] = nm;
      float rs = 0.f;
#pragma unroll
      for (int ct = 0; ct < 4; ++ct) {
        float p = __expf(s[ct][r] - nm);
        pr[ct][r] = p;
        rs += p;
      }
#pragma unroll
      for (int d = 1; d < 16; d <<= 1) rs += __shfl_xor(rs, d, 64);
      l[r] = l[r] * alpha + rs;
#pragma unroll
      for (int dt = 0; dt < 4; ++dt) o[dt][r] *= alpha;
    }

    // P -> LDS (bf16, A-layout source); wave-local, no barrier needed
#pragma unroll
    for (int ct = 0; ct < 4; ++ct)
#pragma unroll
      for (int r = 0; r < 4; ++r) {
        int row = quad * 4 + r;
        int col = ct * 16 + l15;
        myP[row * 64 + (((col >> 3) ^ (row & 7)) << 3) + (col & 7)] = f2bf(pr[ct][r]);
      }

    // O += P V
#pragma unroll
    for (int ks = 0; ks < 2; ++ks) {
      int c = ks * 4 + quad;
      bf16x8 pf = *(const bf16x8*)(&myP[l15 * 64 + ((c ^ (l15 & 7)) << 3)]);
#pragma unroll
      for (int dt = 0; dt < 4; ++dt) {
        int row = dt * 16 + l15;
        bf16x8 vf = *(const bf16x8*)(&Vt[row * 64 + ((c ^ (row & 7)) << 3)]);
        o[dt] = MFMA16(pf, vf, o[dt]);
      }
    }
  }

  float* Zh = Z + h * (BS_TOK * HD);
#pragma unroll
  for (int r = 0; r < 4; ++r) {
    float inv = 1.0f / l[r];
    int qrow = q0 + wv * 16 + quad * 4 + r;
#pragma unroll
    for (int dt = 0; dt < 4; ++dt)
      Zh[qrow * HD + dt * 16 + l15] = o[dt][r] * inv;
  }
}

// ------------------------------------------------- MH = Wo[768x768] * Zflat[768x2048]
__global__ __launch_bounds__(256) void gemm_out_kernel(const float* __restrict__ Wo,
                                                       const float* __restrict__ Zc,
                                                       float* __restrict__ MH) {
  __shared__ float As[16][68];
  __shared__ float Bs[16][68];
  const int n0 = blockIdx.x * 64;  // j cols (2048 -> 32 tiles)
  const int m0 = blockIdx.y * 64;  // e rows (768 -> 12 tiles)
  const int tid = threadIdx.x;
  const int tx = tid & 15, ty = tid >> 4;
  const int arow = tid >> 2, ak4 = (tid & 3) << 2;
  const int bn = tid & 63, bk0 = (tid >> 6) << 2;
  float acc[4][4] = {};
  for (int k0 = 0; k0 < EMB; k0 += 16) {
    float4 av = *(const float4*)(Wo + (m0 + arow) * EMB + k0 + ak4);
    As[ak4 + 0][arow] = av.x;
    As[ak4 + 1][arow] = av.y;
    As[ak4 + 2][arow] = av.z;
    As[ak4 + 3][arow] = av.w;
#pragma unroll
    for (int j = 0; j < 4; ++j)
      Bs[bk0 + j][bn] = Zc[(k0 + bk0 + j) * BS_TOK + n0 + bn];
    __syncthreads();
#pragma unroll
    for (int kk = 0; kk < 16; ++kk) {
      float4 a4 = *(const float4*)&As[kk][ty << 2];
      float4 b4 = *(const float4*)&Bs[kk][tx << 2];
      FMA44(acc, a4, b4);
    }
    __syncthreads();
  }
#pragma unroll
  for (int i = 0; i < 4; ++i) {
    float4 ov = make_float4(acc[i][0], acc[i][1], acc[i][2], acc[i][3]);
    *(float4*)(MH + (m0 + (ty << 2) + i) * BS_TOK + n0 + (tx << 2)) = ov;
  }
}

// ------------------------------------------------- FFN = L1[2048x768] * fw^T + fb
__global__ __launch_bounds__(256) void gemm_ffn_kernel(const float* __restrict__ L1,
                                                       const float* __restrict__ Fw,
                                                       const float* __restrict__ Fb,
                                                       float* __restrict__ Out) {
  __shared__ float As[16][68];
  __shared__ float Bs[16][68];
  const int m0 = blockIdx.x * 64;  // token tile (32)
  const int n0 = blockIdx.y * 64;  // out-feature tile (12)
  const int tid = threadIdx.x;
  const int tx = tid & 15, ty = tid >> 4;
  const int arow = tid >> 2, ak4 = (tid & 3) << 2;
  const int bn = tid & 63, bk0 = (tid >> 6) << 2;
  float acc[4][4] = {};
  for (int k0 = 0; k0 < EMB; k0 += 16) {
    float4 av = *(const float4*)(L1 + (m0 + arow) * EMB + k0 + ak4);
    As[ak4 + 0][arow] = av.x;
    As[ak4 + 1][arow] = av.y;
    As[ak4 + 2][arow] = av.z;
    As[ak4 + 3][arow] = av.w;
    {  // fw[o][k]: contiguous in k for fixed o=n0+bn
      float4 bv = *(const float4*)(Fw + (n0 + bn) * EMB + k0 + bk0);
      Bs[bk0 + 0][bn] = bv.x;
      Bs[bk0 + 1][bn] = bv.y;
      Bs[bk0 + 2][bn] = bv.z;
      Bs[bk0 + 3][bn] = bv.w;
    }
    __syncthreads();
#pragma unroll
    for (int kk = 0; kk < 16; ++kk) {
      float4 a4 = *(const float4*)&As[kk][ty << 2];
      float4 b4 = *(const float4*)&Bs[kk][tx << 2];
      FMA44(acc, a4, b4);
    }
    __syncthreads();
  }
#pragma unroll
  for (int i = 0; i < 4; ++i) {
    float4 ov;
    ov.x = acc[i][0] + Fb[n0 + (tx << 2) + 0];
    ov.y = acc[i][1] + Fb[n0 + (tx << 2) + 1];
    ov.z = acc[i][2] + Fb[n0 + (tx << 2) + 2];
    ov.w = acc[i][3] + Fb[n0 + (tx << 2) + 3];
    *(float4*)(Out + (m0 + (ty << 2) + i) * EMB + n0 + (tx << 2)) = ov;
  }
}

// ------------------------------------------------- LN(Xa + Xb) row-wise over 768
__global__ __launch_bounds__(256) void ln_kernel(const float* __restrict__ Xa,
                                                 const float* __restrict__ Xb,
                                                 const float* __restrict__ g,
                                                 const float* __restrict__ bb,
                                                 float* __restrict__ Out) {
  __shared__ float red[4];
  const int t = blockIdx.x;
  const int tid = threadIdx.x;
  float v[3];
  float s = 0.f;
#pragma unroll
  for (int i = 0; i < 3; ++i) {
    int e = tid + i * 256;
    v[i] = Xa[t * EMB + e] + Xb[t * EMB + e];
    s += v[i];
  }
#pragma unroll
  for (int o = 32; o > 0; o >>= 1) s += __shfl_xor(s, o, 64);
  if ((tid & 63) == 0) red[tid >> 6] = s;
  __syncthreads();
  float mu = (red[0] + red[1] + red[2] + red[3]) * (1.0f / EMB);
  float q = 0.f;
#pragma unroll
  for (int i = 0; i < 3; ++i) {
    float d = v[i] - mu;
    q += d * d;
  }
#pragma unroll
  for (int o = 32; o > 0; o >>= 1) q += __shfl_xor(q, o, 64);
  __syncthreads();  // done reading red
  if ((tid & 63) == 0) red[tid >> 6] = q;
  __syncthreads();
  float var = (red[0] + red[1] + red[2] + red[3]) * (1.0f / EMB);
  float r = rsqrtf(var + 1e-5f);
#pragma unroll
  for (int i = 0; i < 3; ++i) {
    int e = tid + i * 256;
    Out[t * EMB + e] = (v[i] - mu) * r * g[e] + bb[e];
  }
}

extern "C" void kernel_launch(void* const* d_in, const int* in_sizes, int n_in,
                              void* d_out, int out_size, void* d_ws, size_t ws_size,
                              hipStream_t stream) {
  const float* tok = (const float*)d_in[0];
  const float* wq = (const float*)d_in[1];
  const float* wo = (const float*)d_in[2];
  const float* g1 = (const float*)d_in[3];
  const float* b1 = (const float*)d_in[4];
  const float* fw = (const float*)d_in[5];
  const float* fb = (const float*)d_in[6];
  const float* g2 = (const float*)d_in[7];
  const float* b2 = (const float*)d_in[8];
  const int NB = BS_TOK * EMB;  // 1572864 elems per activation buffer
  float* X = (float*)d_ws;
  float* Qb = X + NB;
  float* Zb = X + 2 * NB;

  pe_add_kernel<<<NB / 256, 256, 0, stream>>>(tok, X);
  for (int it = 0; it < 13; ++it) {
    int l = (it == 0) ? 0 : it - 1;  // layer 0 applied twice (faithful)
    const float* wql = wq + (size_t)l * (NH * EMB * HD);
    const float* wol = wo + (size_t)l * (EMB * NH * HD);
    const float* fwl = fw + (size_t)l * (EMB * EMB);
    gemm_q_kernel<<<dim3(32, 12), 256, 0, stream>>>(X, wql, Qb);
    attn_mfma_kernel<<<dim3(64, 12), 128, 0, stream>>>(Qb, Zb);
    gemm_out_kernel<<<dim3(32, 12), 256, 0, stream>>>(wol, Zb, Qb);    // MH -> Qb
    ln_kernel<<<BS_TOK, 256, 0, stream>>>(X, Qb, g1 + l * EMB, b1 + l * EMB, Zb);  // L1 -> Zb
    gemm_ffn_kernel<<<dim3(32, 12), 256, 0, stream>>>(Zb, fwl, fb + l * EMB, X);   // FFN -> X
    float* ln2_dst = (it == 12) ? (float*)d_out : Qb;
    ln_kernel<<<BS_TOK, 256, 0, stream>>>(Zb, X, g2 + l * EMB, b2 + l * EMB, ln2_dst);
    float* tmp = X;
    X = Qb;
    Qb = tmp;
  }
}

// Round 4
// 1887.915 us; speedup vs baseline: 3.1563x; 1.8128x over previous
//
#include <hip/hip_runtime.h>
#include <hip/hip_bf16.h>

// BERT stack: L=12(+1 dup of layer0), H=12, E=768, D=64, B=4, S=512 -> BS=2048 tokens.
// Faithful bugs preserved:
//  - attention flattens batch: 2048 tokens attend to each other globally, q==k==v
//  - zc = z.reshape(768,2048) is a FLAT VIEW of z[H][N][D]  (no transpose)
//  - mh = (wo@zc).reshape(B,S,E) is a FLAT VIEW of mh_mat[768][2048]
//  - pe: p = 10000 for e<384 else 10001; even e -> sin, odd -> cos; s = t % 512
// Inputs/outputs fp32. All GEMMs + attention in bf16 MFMA (fp32 accumulate);
// residual/LN chain kept in fp32. Q and Z activations stored as bf16.

#define BS_TOK 2048
#define EMB 768
#define NH 12
#define HD 64

typedef __attribute__((ext_vector_type(8))) short bf16x8;
typedef __attribute__((ext_vector_type(4))) float f32x4;

__device__ __forceinline__ short f2bf(float f) {
  union { float f; unsigned u; } v;
  v.f = f;
  unsigned r = (v.u + 0x7FFF + ((v.u >> 16) & 1)) >> 16;  // RNE
  return (short)(unsigned short)r;
}

#define MFMA16(a, b, c) __builtin_amdgcn_mfma_f32_16x16x32_bf16(a, b, c, 0, 0, 0)
// XOR-swizzled LDS address for [r][k] tiles with 64-elem rows (zero-conflict, validated r3)
#define SW64(r, k) ((r) * 64 + ((((k) >> 3) ^ ((r) & 7)) << 3) + ((k) & 7))

// ---------------------------------------------------------------- pe + tokens
__global__ __launch_bounds__(256) void pe_add_kernel(const float* __restrict__ tok,
                                                     float* __restrict__ X) {
  int idx = blockIdx.x * 256 + threadIdx.x;   // < 2048*768
  int e = idx % EMB;
  int t = idx / EMB;
  int s = t & 511;                            // t = b*512 + s
  float p = (e < 384) ? 10000.0f : 10001.0f;  // 10000 XOR ((2e)//768)
  float ang = (float)s / p;
  float pe = (e & 1) ? cosf(ang) : sinf(ang);
  X[idx] = tok[idx] + pe;
}

// ---------------- staging helpers (64 rows x 64 k per tile, 256 threads) ----
// direct: dst[r][k] <- fp32 src[row0+r][k0+k], k contiguous in src
__device__ __forceinline__ void stage_direct_f32(const float* __restrict__ src, int ld,
                                                 int row0, int k0, short* dst, int tid) {
  int r = tid >> 2, kb = (tid & 3) << 4;
  const float* p = src + (size_t)(row0 + r) * ld + k0 + kb;
  float4 x0 = *(const float4*)(p + 0);
  float4 x1 = *(const float4*)(p + 4);
  float4 x2 = *(const float4*)(p + 8);
  float4 x3 = *(const float4*)(p + 12);
  bf16x8 a, b;
  a[0] = f2bf(x0.x); a[1] = f2bf(x0.y); a[2] = f2bf(x0.z); a[3] = f2bf(x0.w);
  a[4] = f2bf(x1.x); a[5] = f2bf(x1.y); a[6] = f2bf(x1.z); a[7] = f2bf(x1.w);
  b[0] = f2bf(x2.x); b[1] = f2bf(x2.y); b[2] = f2bf(x2.z); b[3] = f2bf(x2.w);
  b[4] = f2bf(x3.x); b[5] = f2bf(x3.y); b[6] = f2bf(x3.z); b[7] = f2bf(x3.w);
  int g = kb >> 3;
  *(bf16x8*)&dst[r * 64 + ((g ^ (r & 7)) << 3)] = a;
  *(bf16x8*)&dst[r * 64 + (((g + 1) ^ (r & 7)) << 3)] = b;
}

// transpose: dst[n][k] <- fp32 src[k0+k][col0+n], n contiguous in src
__device__ __forceinline__ void stage_trans_f32(const float* __restrict__ src, int ld,
                                                int k0, int col0, short* dst, int tid) {
  int kk = tid >> 2, nb = (tid & 3) << 4;
  const float* p = src + (size_t)(k0 + kk) * ld + col0 + nb;
  float4 x0 = *(const float4*)(p + 0);
  float4 x1 = *(const float4*)(p + 4);
  float4 x2 = *(const float4*)(p + 8);
  float4 x3 = *(const float4*)(p + 12);
  float v[16] = {x0.x, x0.y, x0.z, x0.w, x1.x, x1.y, x1.z, x1.w,
                 x2.x, x2.y, x2.z, x2.w, x3.x, x3.y, x3.z, x3.w};
#pragma unroll
  for (int j = 0; j < 16; ++j) dst[SW64(nb + j, kk)] = f2bf(v[j]);
}

// transpose: dst[n][k] <- bf16 src[k0+k][col0+n], n contiguous in src
__device__ __forceinline__ void stage_trans_bf16(const short* __restrict__ src, int ld,
                                                 int k0, int col0, short* dst, int tid) {
  int kk = tid >> 2, nb = (tid & 3) << 4;
  const short* p = src + (size_t)(k0 + kk) * ld + col0 + nb;
  bf16x8 x0 = *(const bf16x8*)(p + 0);
  bf16x8 x1 = *(const bf16x8*)(p + 8);
#pragma unroll
  for (int j = 0; j < 8; ++j) dst[SW64(nb + j, kk)] = x0[j];
#pragma unroll
  for (int j = 0; j < 8; ++j) dst[SW64(nb + 8 + j, kk)] = x1[j];
}

// MFMA inner product over one 64x64 staged tile pair (per wave: 16 rows x 64 cols)
#define GEMM_TILE_COMPUTE(As, Bs, acc)                                              \
  {                                                                                 \
    _Pragma("unroll") for (int s = 0; s < 2; ++s) {                                 \
      int ra = (w << 4) + l15;                                                      \
      bf16x8 af = *(const bf16x8*)&As[ra * 64 + ((((s << 2) + quad) ^ (ra & 7)) << 3)]; \
      _Pragma("unroll") for (int nt = 0; nt < 4; ++nt) {                            \
        int rb = (nt << 4) + l15;                                                   \
        bf16x8 bf = *(const bf16x8*)&Bs[rb * 64 + ((((s << 2) + quad) ^ (rb & 7)) << 3)]; \
        acc[nt] = MFMA16(af, bf, acc[nt]);                                          \
      }                                                                             \
    }                                                                               \
  }

// ------------------------------------------------- Q = X[2048x768] * Wq -> bf16 [H][2048][64]
__global__ __launch_bounds__(256) void gemm_q_kernel(const float* __restrict__ X,
                                                     const float* __restrict__ Wq,
                                                     short* __restrict__ Qo) {
  __shared__ short As[64 * 64];
  __shared__ short Bs[64 * 64];
  const int m0 = blockIdx.x * 64;  // token tile
  const int h = blockIdx.y;        // head (N-tile of 64 = HD)
  const int tid = threadIdx.x;
  const int w = tid >> 6, lane = tid & 63, l15 = lane & 15, quad = lane >> 4;
  const float* wqh = Wq + (size_t)h * (EMB * HD);
  f32x4 acc[4] = {(f32x4){0, 0, 0, 0}, (f32x4){0, 0, 0, 0},
                  (f32x4){0, 0, 0, 0}, (f32x4){0, 0, 0, 0}};
  for (int k0 = 0; k0 < EMB; k0 += 64) {
    stage_direct_f32(X, EMB, m0, k0, As, tid);
    stage_trans_f32(wqh, HD, k0, 0, Bs, tid);  // Bs[d][k] <- Wq[k][d]
    __syncthreads();
    GEMM_TILE_COMPUTE(As, Bs, acc);
    __syncthreads();
  }
  short* qo = Qo + (size_t)h * (BS_TOK * HD);
#pragma unroll
  for (int nt = 0; nt < 4; ++nt)
#pragma unroll
    for (int r = 0; r < 4; ++r)
      qo[(size_t)(m0 + (w << 4) + (quad << 2) + r) * HD + (nt << 4) + l15] =
          f2bf(acc[nt][r]);
}

// ------------------------------------------------- flash attention, bf16 in/out
// Block = 128 thr (2 waves), Q-tile 32 (16 rows/wave), K-tile 64, register prefetch.
__global__ __launch_bounds__(128) void attn_mfma_kernel(const short* __restrict__ Q,
                                                        short* __restrict__ Z) {
  __shared__ short Ks[64 * 64];      // K[key][d]
  __shared__ short Vt[64 * 64];      // V^T[d][key]
  __shared__ short Pw[2 * 16 * 64];  // per-wave P[qrow][key]
  const int h = blockIdx.y;
  const int q0 = blockIdx.x * 32;
  const int tid = threadIdx.x;
  const int lane = tid & 63;
  const int wv = tid >> 6;
  const int l15 = lane & 15;
  const int quad = lane >> 4;
  const short* Qh = Q + (size_t)h * (BS_TOK * HD);
  short* myP = Pw + wv * 16 * 64;

  // Q A-fragments (bf16 direct): rows q0+wv*16+l15
  bf16x8 qf[2];
  {
    const short* qp = Qh + (size_t)(q0 + wv * 16 + l15) * HD + quad * 8;
    qf[0] = *(const bf16x8*)(qp);
    qf[1] = *(const bf16x8*)(qp + 32);
  }

  f32x4 o[4];
  float m[4], l[4];
#pragma unroll
  for (int r = 0; r < 4; ++r) {
    o[r] = (f32x4){0.f, 0.f, 0.f, 0.f};
    m[r] = -1e30f;
    l[r] = 0.f;
  }

  // prefetch tile 0: lane covers key=lane, d = wv*32..+31 (32 bf16 = 4 x b128)
  bf16x8 t4[4];
  {
    const short* src = Qh + (size_t)lane * HD + wv * 32;
#pragma unroll
    for (int i = 0; i < 4; ++i) t4[i] = *(const bf16x8*)(src + i * 8);
  }

  for (int kt = 0; kt < 32; ++kt) {
    __syncthreads();  // previous iteration's LDS reads done
    {
#pragma unroll
      for (int i = 0; i < 4; ++i) {  // Ks[key=lane][d-group], b128 swizzled
        int c = wv * 4 + i;
        *(bf16x8*)(&Ks[lane * 64 + ((c ^ (lane & 7)) << 3)]) = t4[i];
      }
#pragma unroll
      for (int j = 0; j < 32; ++j) {  // Vt[d][key=lane] transpose, scalar
        int d = wv * 32 + j;
        Vt[SW64(d, lane)] = t4[j >> 3][j & 7];
      }
    }
    __syncthreads();
    if (kt < 31) {  // prefetch next tile; latency overlaps compute below
      const short* src = Qh + (size_t)((kt + 1) * 64 + lane) * HD + wv * 32;
#pragma unroll
      for (int i = 0; i < 4; ++i) t4[i] = *(const bf16x8*)(src + i * 8);
    }

    // S = Q K^T / 8  (4 col-tiles of 16 keys)
    f32x4 s[4];
#pragma unroll
    for (int ct = 0; ct < 4; ++ct) {
      f32x4 acc = (f32x4){0.f, 0.f, 0.f, 0.f};
#pragma unroll
      for (int ks = 0; ks < 2; ++ks) {
        int row = ct * 16 + l15;
        int c = ks * 4 + quad;
        bf16x8 kf = *(const bf16x8*)(&Ks[row * 64 + ((c ^ (row & 7)) << 3)]);
        acc = MFMA16(qf[ks], kf, acc);
      }
      s[ct] = acc;
    }

    // online softmax: lane owns rows quad*4+r, col l15 within each col-tile
    float pr[4][4];
#pragma unroll
    for (int r = 0; r < 4; ++r) {
      float tm = -1e30f;
#pragma unroll
      for (int ct = 0; ct < 4; ++ct) {
        s[ct][r] *= 0.125f;
        tm = fmaxf(tm, s[ct][r]);
      }
#pragma unroll
      for (int d = 1; d < 16; d <<= 1) tm = fmaxf(tm, __shfl_xor(tm, d, 64));
      float nm = fmaxf(m[r], tm);
      float alpha = __expf(m[r] - nm);
      m[r] = nm;
      float rs = 0.f;
#pragma unroll
      for (int ct = 0; ct < 4; ++ct) {
        float p = __expf(s[ct][r] - nm);
        pr[ct][r] = p;
        rs += p;
      }
#pragma unroll
      for (int d = 1; d < 16; d <<= 1) rs += __shfl_xor(rs, d, 64);
      l[r] = l[r] * alpha + rs;
#pragma unroll
      for (int dt = 0; dt < 4; ++dt) o[dt][r] *= alpha;
    }

    // P -> LDS (bf16, A-layout source); wave-local, no barrier needed
#pragma unroll
    for (int ct = 0; ct < 4; ++ct)
#pragma unroll
      for (int r = 0; r < 4; ++r) {
        int row = quad * 4 + r;
        int col = ct * 16 + l15;
        myP[SW64(row, col)] = f2bf(pr[ct][r]);
      }

    // O += P V
#pragma unroll
    for (int ks = 0; ks < 2; ++ks) {
      int c = ks * 4 + quad;
      bf16x8 pf = *(const bf16x8*)(&myP[l15 * 64 + ((c ^ (l15 & 7)) << 3)]);
#pragma unroll
      for (int dt = 0; dt < 4; ++dt) {
        int row = dt * 16 + l15;
        bf16x8 vf = *(const bf16x8*)(&Vt[row * 64 + ((c ^ (row & 7)) << 3)]);
        o[dt] = MFMA16(pf, vf, o[dt]);
      }
    }
  }

  short* Zh = Z + (size_t)h * (BS_TOK * HD);
#pragma unroll
  for (int r = 0; r < 4; ++r) {
    float inv = 1.0f / l[r];
    int qrow = q0 + wv * 16 + quad * 4 + r;
#pragma unroll
    for (int dt = 0; dt < 4; ++dt)
      Zh[(size_t)qrow * HD + dt * 16 + l15] = f2bf(o[dt][r] * inv);
  }
}

// ------------------------------------------------- MH = Wo[768x768] * Zflat[768x2048] (fp32 out)
__global__ __launch_bounds__(256) void gemm_out_kernel(const float* __restrict__ Wo,
                                                       const short* __restrict__ Zc,
                                                       float* __restrict__ MH) {
  __shared__ short As[64 * 64];
  __shared__ short Bs[64 * 64];
  const int n0 = blockIdx.x * 64;  // j cols (2048)
  const int m0 = blockIdx.y * 64;  // e rows (768)
  const int tid = threadIdx.x;
  const int w = tid >> 6, lane = tid & 63, l15 = lane & 15, quad = lane >> 4;
  f32x4 acc[4] = {(f32x4){0, 0, 0, 0}, (f32x4){0, 0, 0, 0},
                  (f32x4){0, 0, 0, 0}, (f32x4){0, 0, 0, 0}};
  for (int k0 = 0; k0 < EMB; k0 += 64) {
    stage_direct_f32(Wo, EMB, m0, k0, As, tid);
    stage_trans_bf16(Zc, BS_TOK, k0, n0, Bs, tid);  // Bs[n][k] <- Zc[k][n]
    __syncthreads();
    GEMM_TILE_COMPUTE(As, Bs, acc);
    __syncthreads();
  }
#pragma unroll
  for (int nt = 0; nt < 4; ++nt)
#pragma unroll
    for (int r = 0; r < 4; ++r)
      MH[(size_t)(m0 + (w << 4) + (quad << 2) + r) * BS_TOK + n0 + (nt << 4) + l15] =
          acc[nt][r];
}

// ------------------------------------------------- FFN = L1[2048x768] * fw^T + fb (fp32 out)
__global__ __launch_bounds__(256) void gemm_ffn_kernel(const float* __restrict__ L1,
                                                       const float* __restrict__ Fw,
                                                       const float* __restrict__ Fb,
                                                       float* __restrict__ Out) {
  __shared__ short As[64 * 64];
  __shared__ short Bs[64 * 64];
  const int m0 = blockIdx.x * 64;  // token tile (32)
  const int n0 = blockIdx.y * 64;  // out-feature tile (12)
  const int tid = threadIdx.x;
  const int w = tid >> 6, lane = tid & 63, l15 = lane & 15, quad = lane >> 4;
  f32x4 acc[4] = {(f32x4){0, 0, 0, 0}, (f32x4){0, 0, 0, 0},
                  (f32x4){0, 0, 0, 0}, (f32x4){0, 0, 0, 0}};
  for (int k0 = 0; k0 < EMB; k0 += 64) {
    stage_direct_f32(L1, EMB, m0, k0, As, tid);
    stage_direct_f32(Fw, EMB, n0, k0, Bs, tid);  // fw[o][k], k contiguous
    __syncthreads();
    GEMM_TILE_COMPUTE(As, Bs, acc);
    __syncthreads();
  }
#pragma unroll
  for (int nt = 0; nt < 4; ++nt) {
    float bias = Fb[n0 + (nt << 4) + l15];
#pragma unroll
    for (int r = 0; r < 4; ++r)
      Out[(size_t)(m0 + (w << 4) + (quad << 2) + r) * EMB + n0 + (nt << 4) + l15] =
          acc[nt][r] + bias;
  }
}

// ------------------------------------------------- LN(Xa + Xb) row-wise over 768
__global__ __launch_bounds__(256) void ln_kernel(const float* __restrict__ Xa,
                                                 const float* __restrict__ Xb,
                                                 const float* __restrict__ g,
                                                 const float* __restrict__ bb,
                                                 float* __restrict__ Out) {
  __shared__ float red[4];
  const int t = blockIdx.x;
  const int tid = threadIdx.x;
  float v[3];
  float s = 0.f;
#pragma unroll
  for (int i = 0; i < 3; ++i) {
    int e = tid + i * 256;
    v[i] = Xa[t * EMB + e] + Xb[t * EMB + e];
    s += v[i];
  }
#pragma unroll
  for (int o = 32; o > 0; o >>= 1) s += __shfl_xor(s, o, 64);
  if ((tid & 63) == 0) red[tid >> 6] = s;
  __syncthreads();
  float mu = (red[0] + red[1] + red[2] + red[3]) * (1.0f / EMB);
  float q = 0.f;
#pragma unroll
  for (int i = 0; i < 3; ++i) {
    float d = v[i] - mu;
    q += d * d;
  }
#pragma unroll
  for (int o = 32; o > 0; o >>= 1) q += __shfl_xor(q, o, 64);
  __syncthreads();  // done reading red
  if ((tid & 63) == 0) red[tid >> 6] = q;
  __syncthreads();
  float var = (red[0] + red[1] + red[2] + red[3]) * (1.0f / EMB);
  float r = rsqrtf(var + 1e-5f);
#pragma unroll
  for (int i = 0; i < 3; ++i) {
    int e = tid + i * 256;
    Out[t * EMB + e] = (v[i] - mu) * r * g[e] + bb[e];
  }
}

extern "C" void kernel_launch(void* const* d_in, const int* in_sizes, int n_in,
                              void* d_out, int out_size, void* d_ws, size_t ws_size,
                              hipStream_t stream) {
  const float* tok = (const float*)d_in[0];
  const float* wq = (const float*)d_in[1];
  const float* wo = (const float*)d_in[2];
  const float* g1 = (const float*)d_in[3];
  const float* b1 = (const float*)d_in[4];
  const float* fw = (const float*)d_in[5];
  const float* fb = (const float*)d_in[6];
  const float* g2 = (const float*)d_in[7];
  const float* b2 = (const float*)d_in[8];
  const int NB = BS_TOK * EMB;  // 1572864 elems
  float* bufA = (float*)d_ws;        // X / X'
  float* bufB = bufA + NB;           // MH, then FFN
  float* bufC = bufB + NB;           // L1
  short* Qbf = (short*)(bufC + NB);  // Q bf16 [H][2048][64]
  short* Zbf = Qbf + NB;             // Z bf16 (flat view = Zc[768][2048])

  pe_add_kernel<<<NB / 256, 256, 0, stream>>>(tok, bufA);
  for (int it = 0; it < 13; ++it) {
    int l = (it == 0) ? 0 : it - 1;  // layer 0 applied twice (faithful)
    const float* wql = wq + (size_t)l * (NH * EMB * HD);
    const float* wol = wo + (size_t)l * (EMB * NH * HD);
    const float* fwl = fw + (size_t)l * (EMB * EMB);
    gemm_q_kernel<<<dim3(32, NH), 256, 0, stream>>>(bufA, wql, Qbf);
    attn_mfma_kernel<<<dim3(64, NH), 128, 0, stream>>>(Qbf, Zbf);
    gemm_out_kernel<<<dim3(32, 12), 256, 0, stream>>>(wol, Zbf, bufB);
    ln_kernel<<<BS_TOK, 256, 0, stream>>>(bufA, bufB, g1 + l * EMB, b1 + l * EMB, bufC);
    gemm_ffn_kernel<<<dim3(32, 12), 256, 0, stream>>>(bufC, fwl, fb + l * EMB, bufB);
    float* ln2_dst = (it == 12) ? (float*)d_out : bufA;
    ln_kernel<<<BS_TOK, 256, 0, stream>>>(bufC, bufB, g2 + l * EMB, b2 + l * EMB, ln2_dst);
  }
}

// Round 5
// 1607.197 us; speedup vs baseline: 3.7075x; 1.1747x over previous
//
#include <hip/hip_runtime.h>
#include <hip/hip_bf16.h>

// BERT stack: L=12(+1 dup of layer0), H=12, E=768, D=64, B=4, S=512 -> BS=2048 tokens.
// Faithful bugs preserved:
//  - attention flattens batch: 2048 tokens attend to each other globally, q==k==v
//  - zc = z.reshape(768,2048) is a FLAT VIEW of z[H][N][D]  (no transpose)
//  - mh = (wo@zc).reshape(B,S,E) is a FLAT VIEW of mh_mat[768][2048]
//  - pe: p = 10000 for e<384 else 10001; even e -> sin, odd -> cos; s = t % 512
// Inputs/outputs fp32. All GEMMs + attention in bf16 MFMA (fp32 accumulate);
// residual/LN chain kept in fp32. Q (both layouts) and Z stored bf16.
// Softmax: no max-subtraction (scores bounded ~25, exp fits fp32 easily),
// denominator deferred to a single end-of-kernel shuffle reduction.

#define BS_TOK 2048
#define EMB 768
#define NH 12
#define HD 64

typedef __attribute__((ext_vector_type(8))) short bf16x8;
typedef __attribute__((ext_vector_type(4))) float f32x4;

__device__ __forceinline__ short f2bf(float f) {
  union { float f; unsigned u; } v;
  v.f = f;
  unsigned r = (v.u + 0x7FFF + ((v.u >> 16) & 1)) >> 16;  // RNE
  return (short)(unsigned short)r;
}
__device__ __forceinline__ float bf2f(short s) {
  union { unsigned u; float f; } v;
  v.u = ((unsigned)(unsigned short)s) << 16;
  return v.f;
}

#define MFMA16(a, b, c) __builtin_amdgcn_mfma_f32_16x16x32_bf16(a, b, c, 0, 0, 0)
// XOR-swizzled LDS address for [r][k] tiles with 64-elem rows (zero-conflict, validated r3/r4)
#define SW64(r, k) ((r) * 64 + ((((k) >> 3) ^ ((r) & 7)) << 3) + ((k) & 7))

// ---------------------------------------------------------------- pe + tokens
__global__ __launch_bounds__(256) void pe_add_kernel(const float* __restrict__ tok,
                                                     float* __restrict__ X) {
  int idx = blockIdx.x * 256 + threadIdx.x;   // < 2048*768
  int e = idx % EMB;
  int t = idx / EMB;
  int s = t & 511;                            // t = b*512 + s
  float p = (e < 384) ? 10000.0f : 10001.0f;  // 10000 XOR ((2e)//768)
  float ang = (float)s / p;
  float pe = (e & 1) ? cosf(ang) : sinf(ang);
  X[idx] = tok[idx] + pe;
}

// ---------------- staging helpers (64 rows x 64 k per tile, 256 threads) ----
// direct: dst[r][k] <- fp32 src[row0+r][k0+k], k contiguous in src
__device__ __forceinline__ void stage_direct_f32(const float* __restrict__ src, int ld,
                                                 int row0, int k0, short* dst, int tid) {
  int r = tid >> 2, kb = (tid & 3) << 4;
  const float* p = src + (size_t)(row0 + r) * ld + k0 + kb;
  float4 x0 = *(const float4*)(p + 0);
  float4 x1 = *(const float4*)(p + 4);
  float4 x2 = *(const float4*)(p + 8);
  float4 x3 = *(const float4*)(p + 12);
  bf16x8 a, b;
  a[0] = f2bf(x0.x); a[1] = f2bf(x0.y); a[2] = f2bf(x0.z); a[3] = f2bf(x0.w);
  a[4] = f2bf(x1.x); a[5] = f2bf(x1.y); a[6] = f2bf(x1.z); a[7] = f2bf(x1.w);
  b[0] = f2bf(x2.x); b[1] = f2bf(x2.y); b[2] = f2bf(x2.z); b[3] = f2bf(x2.w);
  b[4] = f2bf(x3.x); b[5] = f2bf(x3.y); b[6] = f2bf(x3.z); b[7] = f2bf(x3.w);
  int g = kb >> 3;
  *(bf16x8*)&dst[r * 64 + ((g ^ (r & 7)) << 3)] = a;
  *(bf16x8*)&dst[r * 64 + (((g + 1) ^ (r & 7)) << 3)] = b;
}

// transpose: dst[n][k] <- fp32 src[k0+k][col0+n], n contiguous in src
__device__ __forceinline__ void stage_trans_f32(const float* __restrict__ src, int ld,
                                                int k0, int col0, short* dst, int tid) {
  int kk = tid >> 2, nb = (tid & 3) << 4;
  const float* p = src + (size_t)(k0 + kk) * ld + col0 + nb;
  float4 x0 = *(const float4*)(p + 0);
  float4 x1 = *(const float4*)(p + 4);
  float4 x2 = *(const float4*)(p + 8);
  float4 x3 = *(const float4*)(p + 12);
  float v[16] = {x0.x, x0.y, x0.z, x0.w, x1.x, x1.y, x1.z, x1.w,
                 x2.x, x2.y, x2.z, x2.w, x3.x, x3.y, x3.z, x3.w};
#pragma unroll
  for (int j = 0; j < 16; ++j) dst[SW64(nb + j, kk)] = f2bf(v[j]);
}

// transpose: dst[n][k] <- bf16 src[k0+k][col0+n], n contiguous in src
__device__ __forceinline__ void stage_trans_bf16(const short* __restrict__ src, int ld,
                                                 int k0, int col0, short* dst, int tid) {
  int kk = tid >> 2, nb = (tid & 3) << 4;
  const short* p = src + (size_t)(k0 + kk) * ld + col0 + nb;
  bf16x8 x0 = *(const bf16x8*)(p + 0);
  bf16x8 x1 = *(const bf16x8*)(p + 8);
#pragma unroll
  for (int j = 0; j < 8; ++j) dst[SW64(nb + j, kk)] = x0[j];
#pragma unroll
  for (int j = 0; j < 8; ++j) dst[SW64(nb + 8 + j, kk)] = x1[j];
}

// MFMA inner product over one 64x64 staged tile pair (per wave: 16 rows x 64 cols)
#define GEMM_TILE_COMPUTE(As, Bs, acc)                                              \
  {                                                                                 \
    _Pragma("unroll") for (int s = 0; s < 2; ++s) {                                 \
      int ra = (w << 4) + l15;                                                      \
      bf16x8 af = *(const bf16x8*)&As[ra * 64 + ((((s << 2) + quad) ^ (ra & 7)) << 3)]; \
      _Pragma("unroll") for (int nt = 0; nt < 4; ++nt) {                            \
        int rb = (nt << 4) + l15;                                                   \
        bf16x8 bf = *(const bf16x8*)&Bs[rb * 64 + ((((s << 2) + quad) ^ (rb & 7)) << 3)]; \
        acc[nt] = MFMA16(af, bf, acc[nt]);                                          \
      }                                                                             \
    }                                                                               \
  }

// ------------------------------------------------- Q = X[2048x768] * Wq -> bf16 Q + Qt
__global__ __launch_bounds__(256) void gemm_q_kernel(const float* __restrict__ X,
                                                     const float* __restrict__ Wq,
                                                     short* __restrict__ Qo,
                                                     short* __restrict__ Qt) {
  __shared__ short As[64 * 64];
  __shared__ short Bs[64 * 64];
  const int m0 = blockIdx.x * 64;  // token tile
  const int h = blockIdx.y;        // head (N-tile of 64 = HD)
  const int tid = threadIdx.x;
  const int w = tid >> 6, lane = tid & 63, l15 = lane & 15, quad = lane >> 4;
  const float* wqh = Wq + (size_t)h * (EMB * HD);
  f32x4 acc[4] = {(f32x4){0, 0, 0, 0}, (f32x4){0, 0, 0, 0},
                  (f32x4){0, 0, 0, 0}, (f32x4){0, 0, 0, 0}};
  for (int k0 = 0; k0 < EMB; k0 += 64) {
    stage_direct_f32(X, EMB, m0, k0, As, tid);
    stage_trans_f32(wqh, HD, k0, 0, Bs, tid);  // Bs[d][k] <- Wq[k][d]
    __syncthreads();
    GEMM_TILE_COMPUTE(As, Bs, acc);
    __syncthreads();
  }
  // write Q[h][tok][d] + stage tile into As as [tok][d] for transposed Qt write
  short* qo = Qo + (size_t)h * (BS_TOK * HD);
#pragma unroll
  for (int nt = 0; nt < 4; ++nt)
#pragma unroll
    for (int r = 0; r < 4; ++r) {
      short v = f2bf(acc[nt][r]);
      int tokr = (w << 4) + (quad << 2) + r;
      int d = (nt << 4) + l15;
      qo[(size_t)(m0 + tokr) * HD + d] = v;
      As[SW64(tokr, d)] = v;
    }
  __syncthreads();
  {  // Qt[h][d][tok], coalesced b128 stores
    int d = tid >> 2, tok0 = (tid & 3) << 4;
    bf16x8 t0, t1;
#pragma unroll
    for (int j = 0; j < 8; ++j) t0[j] = As[SW64(tok0 + j, d)];
#pragma unroll
    for (int j = 0; j < 8; ++j) t1[j] = As[SW64(tok0 + 8 + j, d)];
    short* qt = Qt + (size_t)h * (HD * BS_TOK) + (size_t)d * BS_TOK + m0 + tok0;
    *(bf16x8*)(qt) = t0;
    *(bf16x8*)(qt + 8) = t1;
  }
}

// ------------------------------------------------- flash attention, bf16 MFMA
// Block = 128 thr (2 waves), Q-tile 32 (16 rows/wave), K-tile 64.
// No-max softmax, deferred denominator; K from Q (contig tile), V from Qt.
__global__ __launch_bounds__(128) void attn_mfma_kernel(const short* __restrict__ Q,
                                                        const short* __restrict__ Qt,
                                                        short* __restrict__ Z) {
  __shared__ short Ks[64 * 64];      // K[key][d]
  __shared__ short Vt[64 * 64];      // V^T[d][key]
  __shared__ short Pw[2 * 16 * 64];  // per-wave P[qrow][key]
  const int h = blockIdx.y;
  const int q0 = blockIdx.x * 32;
  const int tid = threadIdx.x;
  const int lane = tid & 63;
  const int wv = tid >> 6;
  const int l15 = lane & 15;
  const int quad = lane >> 4;
  const short* Qh = Q + (size_t)h * (BS_TOK * HD);
  const short* Qth = Qt + (size_t)h * (HD * BS_TOK);
  short* myP = Pw + wv * 16 * 64;

  // Q A-fragments, pre-scaled by 1/8 (exact exponent shift; folds the /sqrt(64))
  bf16x8 qf[2];
  {
    const short* qp = Qh + (size_t)(q0 + wv * 16 + l15) * HD + quad * 8;
    qf[0] = *(const bf16x8*)(qp);
    qf[1] = *(const bf16x8*)(qp + 32);
#pragma unroll
    for (int k = 0; k < 2; ++k)
#pragma unroll
      for (int j = 0; j < 8; ++j) qf[k][j] = f2bf(bf2f(qf[k][j]) * 0.125f);
  }

  f32x4 o[4];
  float lp[4] = {0.f, 0.f, 0.f, 0.f};
#pragma unroll
  for (int r = 0; r < 4; ++r) o[r] = (f32x4){0.f, 0.f, 0.f, 0.f};

  // chunked, fully-coalesced prefetch of tile 0 (512 b128 chunks per 8KB tile)
  bf16x8 kreg[4], vreg[4];
#pragma unroll
  for (int i = 0; i < 4; ++i) {
    int c = i * 128 + tid;
    kreg[i] = *(const bf16x8*)(Qh + c * 8);                              // contig tile
    vreg[i] = *(const bf16x8*)(Qth + (c >> 3) * BS_TOK + (c & 7) * 8);   // row d=c>>3
  }

  for (int kt = 0; kt < 32; ++kt) {
    __syncthreads();  // previous iteration's LDS reads done
#pragma unroll
    for (int i = 0; i < 4; ++i) {
      int c = i * 128 + tid, row = c >> 3, g = c & 7;
      *(bf16x8*)&Ks[row * 64 + ((g ^ (row & 7)) << 3)] = kreg[i];
      *(bf16x8*)&Vt[row * 64 + ((g ^ (row & 7)) << 3)] = vreg[i];
    }
    __syncthreads();
    if (kt < 31) {  // prefetch next tile; latency hidden behind compute
#pragma unroll
      for (int i = 0; i < 4; ++i) {
        int c = i * 128 + tid;
        kreg[i] = *(const bf16x8*)(Qh + (kt + 1) * 4096 + c * 8);
        vreg[i] = *(const bf16x8*)(Qth + (c >> 3) * BS_TOK + (kt + 1) * 64 + (c & 7) * 8);
      }
    }

    // S = (Q/8) K^T  (4 col-tiles of 16 keys)
    f32x4 s[4];
#pragma unroll
    for (int ct = 0; ct < 4; ++ct) {
      f32x4 acc = (f32x4){0.f, 0.f, 0.f, 0.f};
#pragma unroll
      for (int ks = 0; ks < 2; ++ks) {
        int row = ct * 16 + l15;
        int c = ks * 4 + quad;
        bf16x8 kf = *(const bf16x8*)(&Ks[row * 64 + ((c ^ (row & 7)) << 3)]);
        acc = MFMA16(qf[ks], kf, acc);
      }
      s[ct] = acc;
    }

    // no-max softmax: p = exp(s); per-lane partial denominator only
#pragma unroll
    for (int ct = 0; ct < 4; ++ct)
#pragma unroll
      for (int r = 0; r < 4; ++r) {
        float p = __expf(s[ct][r]);
        lp[r] += p;
        myP[SW64(quad * 4 + r, ct * 16 + l15)] = f2bf(p);
      }

    // O += P V   (wave-local myP; in-wave lgkmcnt ordering, no barrier)
#pragma unroll
    for (int ks = 0; ks < 2; ++ks) {
      int c = ks * 4 + quad;
      bf16x8 pf = *(const bf16x8*)(&myP[l15 * 64 + ((c ^ (l15 & 7)) << 3)]);
#pragma unroll
      for (int dt = 0; dt < 4; ++dt) {
        int row = dt * 16 + l15;
        bf16x8 vf = *(const bf16x8*)(&Vt[row * 64 + ((c ^ (row & 7)) << 3)]);
        o[dt] = MFMA16(pf, vf, o[dt]);
      }
    }
  }

  // single deferred denominator reduction (across the 16 l15 lanes per quad)
#pragma unroll
  for (int r = 0; r < 4; ++r) {
    float t = lp[r];
#pragma unroll
    for (int d = 1; d < 16; d <<= 1) t += __shfl_xor(t, d, 64);
    lp[r] = t;
  }

  short* Zh = Z + (size_t)h * (BS_TOK * HD);
#pragma unroll
  for (int r = 0; r < 4; ++r) {
    float inv = 1.0f / lp[r];
    int qrow = q0 + wv * 16 + quad * 4 + r;
#pragma unroll
    for (int dt = 0; dt < 4; ++dt)
      Zh[(size_t)qrow * HD + dt * 16 + l15] = f2bf(o[dt][r] * inv);
  }
}

// ------------------------------------------------- MH = Wo[768x768] * Zflat[768x2048] (fp32 out)
__global__ __launch_bounds__(256) void gemm_out_kernel(const float* __restrict__ Wo,
                                                       const short* __restrict__ Zc,
                                                       float* __restrict__ MH) {
  __shared__ short As[64 * 64];
  __shared__ short Bs[64 * 64];
  const int n0 = blockIdx.x * 64;  // j cols (2048)
  const int m0 = blockIdx.y * 64;  // e rows (768)
  const int tid = threadIdx.x;
  const int w = tid >> 6, lane = tid & 63, l15 = lane & 15, quad = lane >> 4;
  f32x4 acc[4] = {(f32x4){0, 0, 0, 0}, (f32x4){0, 0, 0, 0},
                  (f32x4){0, 0, 0, 0}, (f32x4){0, 0, 0, 0}};
  for (int k0 = 0; k0 < EMB; k0 += 64) {
    stage_direct_f32(Wo, EMB, m0, k0, As, tid);
    stage_trans_bf16(Zc, BS_TOK, k0, n0, Bs, tid);  // Bs[n][k] <- Zc[k][n]
    __syncthreads();
    GEMM_TILE_COMPUTE(As, Bs, acc);
    __syncthreads();
  }
#pragma unroll
  for (int nt = 0; nt < 4; ++nt)
#pragma unroll
    for (int r = 0; r < 4; ++r)
      MH[(size_t)(m0 + (w << 4) + (quad << 2) + r) * BS_TOK + n0 + (nt << 4) + l15] =
          acc[nt][r];
}

// ------------------------------------------------- FFN = L1[2048x768] * fw^T + fb (fp32 out)
__global__ __launch_bounds__(256) void gemm_ffn_kernel(const float* __restrict__ L1,
                                                       const float* __restrict__ Fw,
                                                       const float* __restrict__ Fb,
                                                       float* __restrict__ Out) {
  __shared__ short As[64 * 64];
  __shared__ short Bs[64 * 64];
  const int m0 = blockIdx.x * 64;  // token tile (32)
  const int n0 = blockIdx.y * 64;  // out-feature tile (12)
  const int tid = threadIdx.x;
  const int w = tid >> 6, lane = tid & 63, l15 = lane & 15, quad = lane >> 4;
  f32x4 acc[4] = {(f32x4){0, 0, 0, 0}, (f32x4){0, 0, 0, 0},
                  (f32x4){0, 0, 0, 0}, (f32x4){0, 0, 0, 0}};
  for (int k0 = 0; k0 < EMB; k0 += 64) {
    stage_direct_f32(L1, EMB, m0, k0, As, tid);
    stage_direct_f32(Fw, EMB, n0, k0, Bs, tid);  // fw[o][k], k contiguous
    __syncthreads();
    GEMM_TILE_COMPUTE(As, Bs, acc);
    __syncthreads();
  }
#pragma unroll
  for (int nt = 0; nt < 4; ++nt) {
    float bias = Fb[n0 + (nt << 4) + l15];
#pragma unroll
    for (int r = 0; r < 4; ++r)
      Out[(size_t)(m0 + (w << 4) + (quad << 2) + r) * EMB + n0 + (nt << 4) + l15] =
          acc[nt][r] + bias;
  }
}

// ------------------------------------------------- LN(Xa + Xb) row-wise over 768
__global__ __launch_bounds__(256) void ln_kernel(const float* __restrict__ Xa,
                                                 const float* __restrict__ Xb,
                                                 const float* __restrict__ g,
                                                 const float* __restrict__ bb,
                                                 float* __restrict__ Out) {
  __shared__ float red[4];
  const int t = blockIdx.x;
  const int tid = threadIdx.x;
  float v[3];
  float s = 0.f;
#pragma unroll
  for (int i = 0; i < 3; ++i) {
    int e = tid + i * 256;
    v[i] = Xa[t * EMB + e] + Xb[t * EMB + e];
    s += v[i];
  }
#pragma unroll
  for (int o = 32; o > 0; o >>= 1) s += __shfl_xor(s, o, 64);
  if ((tid & 63) == 0) red[tid >> 6] = s;
  __syncthreads();
  float mu = (red[0] + red[1] + red[2] + red[3]) * (1.0f / EMB);
  float q = 0.f;
#pragma unroll
  for (int i = 0; i < 3; ++i) {
    float d = v[i] - mu;
    q += d * d;
  }
#pragma unroll
  for (int o = 32; o > 0; o >>= 1) q += __shfl_xor(q, o, 64);
  __syncthreads();  // done reading red
  if ((tid & 63) == 0) red[tid >> 6] = q;
  __syncthreads();
  float var = (red[0] + red[1] + red[2] + red[3]) * (1.0f / EMB);
  float r = rsqrtf(var + 1e-5f);
#pragma unroll
  for (int i = 0; i < 3; ++i) {
    int e = tid + i * 256;
    Out[t * EMB + e] = (v[i] - mu) * r * g[e] + bb[e];
  }
}

extern "C" void kernel_launch(void* const* d_in, const int* in_sizes, int n_in,
                              void* d_out, int out_size, void* d_ws, size_t ws_size,
                              hipStream_t stream) {
  const float* tok = (const float*)d_in[0];
  const float* wq = (const float*)d_in[1];
  const float* wo = (const float*)d_in[2];
  const float* g1 = (const float*)d_in[3];
  const float* b1 = (const float*)d_in[4];
  const float* fw = (const float*)d_in[5];
  const float* fb = (const float*)d_in[6];
  const float* g2 = (const float*)d_in[7];
  const float* b2 = (const float*)d_in[8];
  const int NB = BS_TOK * EMB;  // 1572864 elems
  float* bufA = (float*)d_ws;        // X / X'
  float* bufB = bufA + NB;           // MH, then FFN
  float* bufC = bufB + NB;           // L1
  short* Qbf = (short*)(bufC + NB);  // Q bf16 [H][2048][64]
  short* Zbf = Qbf + NB;             // Z bf16 (flat view = Zc[768][2048])
  short* Qtb = Zbf + NB;             // Qt bf16 [H][64][2048]

  pe_add_kernel<<<NB / 256, 256, 0, stream>>>(tok, bufA);
  for (int it = 0; it < 13; ++it) {
    int l = (it == 0) ? 0 : it - 1;  // layer 0 applied twice (faithful)
    const float* wql = wq + (size_t)l * (NH * EMB * HD);
    const float* wol = wo + (size_t)l * (EMB * NH * HD);
    const float* fwl = fw + (size_t)l * (EMB * EMB);
    gemm_q_kernel<<<dim3(32, NH), 256, 0, stream>>>(bufA, wql, Qbf, Qtb);
    attn_mfma_kernel<<<dim3(64, NH), 128, 0, stream>>>(Qbf, Qtb, Zbf);
    gemm_out_kernel<<<dim3(32, 12), 256, 0, stream>>>(wol, Zbf, bufB);
    ln_kernel<<<BS_TOK, 256, 0, stream>>>(bufA, bufB, g1 + l * EMB, b1 + l * EMB, bufC);
    gemm_ffn_kernel<<<dim3(32, 12), 256, 0, stream>>>(bufC, fwl, fb + l * EMB, bufB);
    float* ln2_dst = (it == 12) ? (float*)d_out : bufA;
    ln_kernel<<<BS_TOK, 256, 0, stream>>>(bufC, bufB, g2 + l * EMB, b2 + l * EMB, ln2_dst);
  }
}

// Round 6
// 1256.624 us; speedup vs baseline: 4.7419x; 1.2790x over previous
//
#include <hip/hip_runtime.h>
#include <hip/hip_bf16.h>

// BERT stack: L=12(+1 dup of layer0), H=12, E=768, D=64, B=4, S=512 -> BS=2048 tokens.
// Faithful bugs preserved:
//  - attention flattens batch: 2048 tokens attend to each other globally, q==k==v
//  - zc = z.reshape(768,2048) is a FLAT VIEW of z[H][N][D]  (no transpose)
//  - mh = (wo@zc).reshape(B,S,E) is a FLAT VIEW of mh_mat[768][2048]
//  - pe: p = 10000 for e<384 else 10001; even e -> sin, odd -> cos; s = t % 512
// Inputs/outputs fp32. All GEMMs + attention bf16 MFMA (fp32 accumulate);
// residual/LN chain fp32. Weights pre-converted to bf16 once per launch;
// LN/PE emit dual fp32+bf16 so no K-loop does any dtype conversion.
// Attention: no-max softmax (scores bounded ~30) => K-split partials are
// purely additive; ksplit=2 doubles occupancy; combine kernel normalizes.

#define BS_TOK 2048
#define EMB 768
#define NH 12
#define HD 64
#define WQN (12 * NH * EMB * HD)  // elems per wq-like weight stack (7077888)

typedef __attribute__((ext_vector_type(8))) short bf16x8;
typedef __attribute__((ext_vector_type(4))) float f32x4;

__device__ __forceinline__ short f2bf(float f) {
  union { float f; unsigned u; } v;
  v.f = f;
  unsigned r = (v.u + 0x7FFF + ((v.u >> 16) & 1)) >> 16;  // RNE
  return (short)(unsigned short)r;
}

#define MFMA16(a, b, c) __builtin_amdgcn_mfma_f32_16x16x32_bf16(a, b, c, 0, 0, 0)
// XOR-swizzled LDS address for [r][k] tiles with 64-elem rows (zero-conflict, validated r3-r5)
#define SW64(r, k) ((r) * 64 + ((((k) >> 3) ^ ((r) & 7)) << 3) + ((k) & 7))

// ---------------------------------------------------------------- weight prep
__global__ __launch_bounds__(256) void cvt_f32_bf16_kernel(const float* __restrict__ src,
                                                           short* __restrict__ dst) {
  int i = (blockIdx.x * 256 + threadIdx.x) * 8;
  float4 a = *(const float4*)(src + i);
  float4 b = *(const float4*)(src + i + 4);
  bf16x8 t;
  t[0] = f2bf(a.x); t[1] = f2bf(a.y); t[2] = f2bf(a.z); t[3] = f2bf(a.w);
  t[4] = f2bf(b.x); t[5] = f2bf(b.y); t[6] = f2bf(b.z); t[7] = f2bf(b.w);
  *(bf16x8*)(dst + i) = t;
}

// wqT[l][h][d][e] <- wq[l][h][e][d], bf16
__global__ __launch_bounds__(256) void wq_trans_kernel(const float* __restrict__ wq,
                                                       short* __restrict__ wqT) {
  __shared__ short T[64 * 64];
  const int et = blockIdx.x;  // e-tile (12)
  const int lh = blockIdx.y;  // l*NH+h (144)
  const int tid = threadIdx.x;
  const float* src = wq + ((size_t)lh * EMB + et * 64) * HD;
  {
    int r = tid >> 2, c16 = (tid & 3) << 4;
    const float* p = src + r * HD + c16;
    float4 x0 = *(const float4*)(p + 0);
    float4 x1 = *(const float4*)(p + 4);
    float4 x2 = *(const float4*)(p + 8);
    float4 x3 = *(const float4*)(p + 12);
    bf16x8 a, b;
    a[0] = f2bf(x0.x); a[1] = f2bf(x0.y); a[2] = f2bf(x0.z); a[3] = f2bf(x0.w);
    a[4] = f2bf(x1.x); a[5] = f2bf(x1.y); a[6] = f2bf(x1.z); a[7] = f2bf(x1.w);
    b[0] = f2bf(x2.x); b[1] = f2bf(x2.y); b[2] = f2bf(x2.z); b[3] = f2bf(x2.w);
    b[4] = f2bf(x3.x); b[5] = f2bf(x3.y); b[6] = f2bf(x3.z); b[7] = f2bf(x3.w);
    int g = c16 >> 3;
    *(bf16x8*)&T[r * 64 + ((g ^ (r & 7)) << 3)] = a;
    *(bf16x8*)&T[r * 64 + (((g + 1) ^ (r & 7)) << 3)] = b;
  }
  __syncthreads();
  {
    int d = tid >> 2, e16 = (tid & 3) << 4;
    bf16x8 t0, t1;
#pragma unroll
    for (int j = 0; j < 8; ++j) t0[j] = T[SW64(e16 + j, d)];
#pragma unroll
    for (int j = 0; j < 8; ++j) t1[j] = T[SW64(e16 + 8 + j, d)];
    short* q = wqT + ((size_t)lh * HD + d) * EMB + et * 64 + e16;
    *(bf16x8*)(q) = t0;
    *(bf16x8*)(q + 8) = t1;
  }
}

// ---------------------------------------------------------------- pe + tokens
__global__ __launch_bounds__(256) void pe_add_kernel(const float* __restrict__ tok,
                                                     float* __restrict__ X,
                                                     short* __restrict__ Xb) {
  int idx = blockIdx.x * 256 + threadIdx.x;   // < 2048*768
  int e = idx % EMB;
  int t = idx / EMB;
  int s = t & 511;                            // t = b*512 + s
  float p = (e < 384) ? 10000.0f : 10001.0f;  // 10000 XOR ((2e)//768)
  float ang = (float)s / p;
  float pe = (e & 1) ? cosf(ang) : sinf(ang);
  float v = tok[idx] + pe;
  X[idx] = v;
  Xb[idx] = f2bf(v);
}

// ---------------- staging helpers (64 rows x 64 k per tile, 256 threads) ----
// direct: dst[r][k] <- bf16 src[row0+r][k0+k], k contiguous in src
__device__ __forceinline__ void stage_direct_bf16(const short* __restrict__ src, int ld,
                                                  int row0, int k0, short* dst, int tid) {
  int r = tid >> 2, kb = (tid & 3) << 4;
  const short* p = src + (size_t)(row0 + r) * ld + k0 + kb;
  bf16x8 x0 = *(const bf16x8*)(p);
  bf16x8 x1 = *(const bf16x8*)(p + 8);
  int g = kb >> 3;
  *(bf16x8*)&dst[r * 64 + ((g ^ (r & 7)) << 3)] = x0;
  *(bf16x8*)&dst[r * 64 + (((g + 1) ^ (r & 7)) << 3)] = x1;
}

// transpose: dst[n][k] <- bf16 src[k0+k][col0+n], n contiguous in src
__device__ __forceinline__ void stage_trans_bf16(const short* __restrict__ src, int ld,
                                                 int k0, int col0, short* dst, int tid) {
  int kk = tid >> 2, nb = (tid & 3) << 4;
  const short* p = src + (size_t)(k0 + kk) * ld + col0 + nb;
  bf16x8 x0 = *(const bf16x8*)(p + 0);
  bf16x8 x1 = *(const bf16x8*)(p + 8);
#pragma unroll
  for (int j = 0; j < 8; ++j) dst[SW64(nb + j, kk)] = x0[j];
#pragma unroll
  for (int j = 0; j < 8; ++j) dst[SW64(nb + 8 + j, kk)] = x1[j];
}

// MFMA inner product over one 64x64 staged tile pair (per wave: 16 rows x 64 cols)
#define GEMM_TILE_COMPUTE(As, Bs, acc)                                              \
  {                                                                                 \
    _Pragma("unroll") for (int s = 0; s < 2; ++s) {                                 \
      int ra = (w << 4) + l15;                                                      \
      bf16x8 af = *(const bf16x8*)&As[ra * 64 + ((((s << 2) + quad) ^ (ra & 7)) << 3)]; \
      _Pragma("unroll") for (int nt = 0; nt < 4; ++nt) {                            \
        int rb = (nt << 4) + l15;                                                   \
        bf16x8 bf = *(const bf16x8*)&Bs[rb * 64 + ((((s << 2) + quad) ^ (rb & 7)) << 3)]; \
        acc[nt] = MFMA16(af, bf, acc[nt]);                                          \
      }                                                                             \
    }                                                                               \
  }

// ------------------------------------------------- Q = Xb[2048x768] * WqT -> bf16 Q + Qt
__global__ __launch_bounds__(256) void gemm_q_kernel(const short* __restrict__ Xb,
                                                     const short* __restrict__ WqT,
                                                     short* __restrict__ Qo,
                                                     short* __restrict__ Qt) {
  __shared__ short As[64 * 64];
  __shared__ short Bs[64 * 64];
  const int m0 = blockIdx.x * 64;  // token tile
  const int h = blockIdx.y;        // head (N-tile of 64 = HD)
  const int tid = threadIdx.x;
  const int w = tid >> 6, lane = tid & 63, l15 = lane & 15, quad = lane >> 4;
  const short* wqh = WqT + (size_t)h * (HD * EMB);  // [d][e]
  f32x4 acc[4] = {(f32x4){0, 0, 0, 0}, (f32x4){0, 0, 0, 0},
                  (f32x4){0, 0, 0, 0}, (f32x4){0, 0, 0, 0}};
  for (int k0 = 0; k0 < EMB; k0 += 64) {
    stage_direct_bf16(Xb, EMB, m0, k0, As, tid);
    stage_direct_bf16(wqh, EMB, 0, k0, Bs, tid);  // Bs[d][k]
    __syncthreads();
    GEMM_TILE_COMPUTE(As, Bs, acc);
    __syncthreads();
  }
  // write Q[h][tok][d] + stage tile into As as [tok][d] for transposed Qt write
  short* qo = Qo + (size_t)h * (BS_TOK * HD);
#pragma unroll
  for (int nt = 0; nt < 4; ++nt)
#pragma unroll
    for (int r = 0; r < 4; ++r) {
      short v = f2bf(acc[nt][r]);
      int tokr = (w << 4) + (quad << 2) + r;
      int d = (nt << 4) + l15;
      qo[(size_t)(m0 + tokr) * HD + d] = v;
      As[SW64(tokr, d)] = v;
    }
  __syncthreads();
  {  // Qt[h][d][tok], coalesced b128 stores
    int d = tid >> 2, tok0 = (tid & 3) << 4;
    bf16x8 t0, t1;
#pragma unroll
    for (int j = 0; j < 8; ++j) t0[j] = As[SW64(tok0 + j, d)];
#pragma unroll
    for (int j = 0; j < 8; ++j) t1[j] = As[SW64(tok0 + 8 + j, d)];
    short* qt = Qt + (size_t)h * (HD * BS_TOK) + (size_t)d * BS_TOK + m0 + tok0;
    *(bf16x8*)(qt) = t0;
    *(bf16x8*)(qt + 8) = t1;
  }
}

// ------------------------------------------------- flash attention, K-split partials
// Block = 128 thr (2 waves), Q-tile 32, K-tile 64, 16 K-tiles per split (z=2).
// No-max softmax: o,l partials are additive across splits; combine normalizes.
__global__ __launch_bounds__(128) void attn_mfma_kernel(const short* __restrict__ Q,
                                                        const short* __restrict__ Qt,
                                                        float* __restrict__ Opart,
                                                        float* __restrict__ Lpart) {
  __shared__ short Ks[64 * 64];      // K[key][d]
  __shared__ short Vt[64 * 64];      // V^T[d][key]
  __shared__ short Pw[2 * 16 * 64];  // per-wave P[qrow][key]
  const int h = blockIdx.y;
  const int q0 = blockIdx.x * 32;
  const int kt0 = blockIdx.z * 16;   // K-tile range for this split
  const int tid = threadIdx.x;
  const int lane = tid & 63;
  const int wv = tid >> 6;
  const int l15 = lane & 15;
  const int quad = lane >> 4;
  const short* Qh = Q + (size_t)h * (BS_TOK * HD);
  const short* Qth = Qt + (size_t)h * (HD * BS_TOK);
  short* myP = Pw + wv * 16 * 64;

  // Q A-fragments (raw; 1/8 scale folded into exp arg)
  bf16x8 qf[2];
  {
    const short* qp = Qh + (size_t)(q0 + wv * 16 + l15) * HD + quad * 8;
    qf[0] = *(const bf16x8*)(qp);
    qf[1] = *(const bf16x8*)(qp + 32);
  }

  f32x4 o[4];
  float lp[4] = {0.f, 0.f, 0.f, 0.f};
#pragma unroll
  for (int r = 0; r < 4; ++r) o[r] = (f32x4){0.f, 0.f, 0.f, 0.f};

  // chunked, fully-coalesced prefetch of first tile
  bf16x8 kreg[4], vreg[4];
#pragma unroll
  for (int i = 0; i < 4; ++i) {
    int c = i * 128 + tid;
    kreg[i] = *(const bf16x8*)(Qh + kt0 * 4096 + c * 8);
    vreg[i] = *(const bf16x8*)(Qth + (c >> 3) * BS_TOK + kt0 * 64 + (c & 7) * 8);
  }

  for (int kt = 0; kt < 16; ++kt) {
    __syncthreads();  // previous iteration's LDS reads done
#pragma unroll
    for (int i = 0; i < 4; ++i) {
      int c = i * 128 + tid, row = c >> 3, g = c & 7;
      *(bf16x8*)&Ks[row * 64 + ((g ^ (row & 7)) << 3)] = kreg[i];
      *(bf16x8*)&Vt[row * 64 + ((g ^ (row & 7)) << 3)] = vreg[i];
    }
    __syncthreads();
    if (kt < 15) {  // prefetch next tile; latency hidden behind compute
      int gt = kt0 + kt + 1;
#pragma unroll
      for (int i = 0; i < 4; ++i) {
        int c = i * 128 + tid;
        kreg[i] = *(const bf16x8*)(Qh + gt * 4096 + c * 8);
        vreg[i] = *(const bf16x8*)(Qth + (c >> 3) * BS_TOK + gt * 64 + (c & 7) * 8);
      }
    }

    // S = Q K^T  (4 col-tiles of 16 keys)
    f32x4 s[4];
#pragma unroll
    for (int ct = 0; ct < 4; ++ct) {
      f32x4 acc = (f32x4){0.f, 0.f, 0.f, 0.f};
#pragma unroll
      for (int ks = 0; ks < 2; ++ks) {
        int row = ct * 16 + l15;
        int c = ks * 4 + quad;
        bf16x8 kf = *(const bf16x8*)(&Ks[row * 64 + ((c ^ (row & 7)) << 3)]);
        acc = MFMA16(qf[ks], kf, acc);
      }
      s[ct] = acc;
    }

    // no-max softmax: p = exp(s/8); per-lane partial denominator only
#pragma unroll
    for (int ct = 0; ct < 4; ++ct)
#pragma unroll
      for (int r = 0; r < 4; ++r) {
        float p = __expf(s[ct][r] * 0.125f);
        lp[r] += p;
        myP[SW64(quad * 4 + r, ct * 16 + l15)] = f2bf(p);
      }

    // O += P V   (wave-local myP; in-wave lgkmcnt ordering, no barrier)
#pragma unroll
    for (int ks = 0; ks < 2; ++ks) {
      int c = ks * 4 + quad;
      bf16x8 pf = *(const bf16x8*)(&myP[l15 * 64 + ((c ^ (l15 & 7)) << 3)]);
#pragma unroll
      for (int dt = 0; dt < 4; ++dt) {
        int row = dt * 16 + l15;
        bf16x8 vf = *(const bf16x8*)(&Vt[row * 64 + ((c ^ (row & 7)) << 3)]);
        o[dt] = MFMA16(pf, vf, o[dt]);
      }
    }
  }

  // per-split denominator reduction + unnormalized partial write
#pragma unroll
  for (int r = 0; r < 4; ++r) {
    float t = lp[r];
#pragma unroll
    for (int d = 1; d < 16; d <<= 1) t += __shfl_xor(t, d, 64);
    lp[r] = t;
  }
  float* Oh = Opart + ((size_t)blockIdx.z * NH + h) * (size_t)(BS_TOK * HD);
  float* Lh = Lpart + ((size_t)blockIdx.z * NH + h) * BS_TOK;
#pragma unroll
  for (int r = 0; r < 4; ++r) {
    int qrow = q0 + wv * 16 + quad * 4 + r;
#pragma unroll
    for (int dt = 0; dt < 4; ++dt)
      Oh[(size_t)qrow * HD + dt * 16 + l15] = o[dt][r];
    if (l15 == 0) Lh[qrow] = lp[r];
  }
}

// ------------------------------------------------- combine split partials -> Z bf16
__global__ __launch_bounds__(256) void attn_combine_kernel(const float* __restrict__ Op,
                                                           const float* __restrict__ Lp,
                                                           short* __restrict__ Z) {
  const int NBH = NH * BS_TOK * HD;
  int idx = blockIdx.x * 256 + threadIdx.x;
  float o = Op[idx] + Op[idx + NBH];
  int hq = idx >> 6;
  float l = Lp[hq] + Lp[hq + NH * BS_TOK];
  Z[idx] = f2bf(o / l);
}

// ------------------------------------------------- MH = Wo[768x768] * Zflat[768x2048] (fp32 out)
__global__ __launch_bounds__(256) void gemm_out_kernel(const short* __restrict__ Wob,
                                                       const short* __restrict__ Zc,
                                                       float* __restrict__ MH) {
  __shared__ short As[64 * 64];
  __shared__ short Bs[64 * 64];
  const int n0 = blockIdx.x * 64;  // j cols (2048)
  const int m0 = blockIdx.y * 64;  // e rows (768)
  const int tid = threadIdx.x;
  const int w = tid >> 6, lane = tid & 63, l15 = lane & 15, quad = lane >> 4;
  f32x4 acc[4] = {(f32x4){0, 0, 0, 0}, (f32x4){0, 0, 0, 0},
                  (f32x4){0, 0, 0, 0}, (f32x4){0, 0, 0, 0}};
  for (int k0 = 0; k0 < EMB; k0 += 64) {
    stage_direct_bf16(Wob, EMB, m0, k0, As, tid);
    stage_trans_bf16(Zc, BS_TOK, k0, n0, Bs, tid);  // Bs[n][k] <- Zc[k][n]
    __syncthreads();
    GEMM_TILE_COMPUTE(As, Bs, acc);
    __syncthreads();
  }
#pragma unroll
  for (int nt = 0; nt < 4; ++nt)
#pragma unroll
    for (int r = 0; r < 4; ++r)
      MH[(size_t)(m0 + (w << 4) + (quad << 2) + r) * BS_TOK + n0 + (nt << 4) + l15] =
          acc[nt][r];
}

// ------------------------------------------------- FFN = L1b[2048x768] * fwb^T + fb (fp32 out)
__global__ __launch_bounds__(256) void gemm_ffn_kernel(const short* __restrict__ L1b,
                                                       const short* __restrict__ Fwb,
                                                       const float* __restrict__ Fb,
                                                       float* __restrict__ Out) {
  __shared__ short As[64 * 64];
  __shared__ short Bs[64 * 64];
  const int m0 = blockIdx.x * 64;  // token tile (32)
  const int n0 = blockIdx.y * 64;  // out-feature tile (12)
  const int tid = threadIdx.x;
  const int w = tid >> 6, lane = tid & 63, l15 = lane & 15, quad = lane >> 4;
  f32x4 acc[4] = {(f32x4){0, 0, 0, 0}, (f32x4){0, 0, 0, 0},
                  (f32x4){0, 0, 0, 0}, (f32x4){0, 0, 0, 0}};
  for (int k0 = 0; k0 < EMB; k0 += 64) {
    stage_direct_bf16(L1b, EMB, m0, k0, As, tid);
    stage_direct_bf16(Fwb, EMB, n0, k0, Bs, tid);  // fw[o][k], k contiguous
    __syncthreads();
    GEMM_TILE_COMPUTE(As, Bs, acc);
    __syncthreads();
  }
#pragma unroll
  for (int nt = 0; nt < 4; ++nt) {
    float bias = Fb[n0 + (nt << 4) + l15];
#pragma unroll
    for (int r = 0; r < 4; ++r)
      Out[(size_t)(m0 + (w << 4) + (quad << 2) + r) * EMB + n0 + (nt << 4) + l15] =
          acc[nt][r] + bias;
  }
}

// ------------------------------------------------- LN(Xa + Xb) -> fp32 + bf16
__global__ __launch_bounds__(256) void ln_kernel(const float* __restrict__ Xa,
                                                 const float* __restrict__ Xb,
                                                 const float* __restrict__ g,
                                                 const float* __restrict__ bb,
                                                 float* __restrict__ Out,
                                                 short* __restrict__ Outb) {
  __shared__ float red[4];
  const int t = blockIdx.x;
  const int tid = threadIdx.x;
  float v[3];
  float s = 0.f;
#pragma unroll
  for (int i = 0; i < 3; ++i) {
    int e = tid + i * 256;
    v[i] = Xa[t * EMB + e] + Xb[t * EMB + e];
    s += v[i];
  }
#pragma unroll
  for (int o = 32; o > 0; o >>= 1) s += __shfl_xor(s, o, 64);
  if ((tid & 63) == 0) red[tid >> 6] = s;
  __syncthreads();
  float mu = (red[0] + red[1] + red[2] + red[3]) * (1.0f / EMB);
  float q = 0.f;
#pragma unroll
  for (int i = 0; i < 3; ++i) {
    float d = v[i] - mu;
    q += d * d;
  }
#pragma unroll
  for (int o = 32; o > 0; o >>= 1) q += __shfl_xor(q, o, 64);
  __syncthreads();  // done reading red
  if ((tid & 63) == 0) red[tid >> 6] = q;
  __syncthreads();
  float var = (red[0] + red[1] + red[2] + red[3]) * (1.0f / EMB);
  float r = rsqrtf(var + 1e-5f);
#pragma unroll
  for (int i = 0; i < 3; ++i) {
    int e = tid + i * 256;
    float res = (v[i] - mu) * r * g[e] + bb[e];
    Out[t * EMB + e] = res;
    Outb[t * EMB + e] = f2bf(res);
  }
}

extern "C" void kernel_launch(void* const* d_in, const int* in_sizes, int n_in,
                              void* d_out, int out_size, void* d_ws, size_t ws_size,
                              hipStream_t stream) {
  const float* tok = (const float*)d_in[0];
  const float* wq = (const float*)d_in[1];
  const float* wo = (const float*)d_in[2];
  const float* g1 = (const float*)d_in[3];
  const float* b1 = (const float*)d_in[4];
  const float* fw = (const float*)d_in[5];
  const float* fb = (const float*)d_in[6];
  const float* g2 = (const float*)d_in[7];
  const float* b2 = (const float*)d_in[8];
  const int NB = BS_TOK * EMB;  // 1572864 elems
  float* bufA = (float*)d_ws;        // X / X'
  float* bufB = bufA + NB;           // MH / FFN; aliased as Opart split 0
  float* bufC = bufB + NB;           // L1;       aliased as Opart split 1
  float* Opart = bufB;               // 2*NB floats, live only attn->combine
  short* XbA = (short*)(bufC + NB);  // bf16 of current X (gemm_q A)
  short* L1b = XbA + NB;             // bf16 of L1 (ffn A)
  short* Qbf = L1b + NB;             // Q bf16 [H][2048][64]
  short* Qtb = Qbf + NB;             // Qt bf16 [H][64][2048]
  short* Zbf = Qtb + NB;             // Z bf16 (flat view = Zc[768][2048])
  short* wqTb = Zbf + NB;            // wqT bf16 [L][H][64][768]
  short* wob = wqTb + WQN;           // wo bf16 [L][768][768]
  short* fwb = wob + WQN;            // fw bf16 [L][768][768]
  float* Lpart = (float*)(fwb + WQN);  // [2][H][2048]

  cvt_f32_bf16_kernel<<<WQN / (256 * 8), 256, 0, stream>>>(wo, wob);
  cvt_f32_bf16_kernel<<<WQN / (256 * 8), 256, 0, stream>>>(fw, fwb);
  wq_trans_kernel<<<dim3(12, 12 * NH), 256, 0, stream>>>(wq, wqTb);
  pe_add_kernel<<<NB / 256, 256, 0, stream>>>(tok, bufA, XbA);
  for (int it = 0; it < 13; ++it) {
    int l = (it == 0) ? 0 : it - 1;  // layer 0 applied twice (faithful)
    gemm_q_kernel<<<dim3(32, NH), 256, 0, stream>>>(
        XbA, wqTb + (size_t)l * (NH * HD * EMB), Qbf, Qtb);
    attn_mfma_kernel<<<dim3(64, NH, 2), 128, 0, stream>>>(Qbf, Qtb, Opart, Lpart);
    attn_combine_kernel<<<NH * BS_TOK * HD / 256, 256, 0, stream>>>(Opart, Lpart, Zbf);
    gemm_out_kernel<<<dim3(32, 12), 256, 0, stream>>>(
        wob + (size_t)l * (EMB * EMB), Zbf, bufB);
    ln_kernel<<<BS_TOK, 256, 0, stream>>>(bufA, bufB, g1 + l * EMB, b1 + l * EMB,
                                          bufC, L1b);
    gemm_ffn_kernel<<<dim3(32, 12), 256, 0, stream>>>(
        L1b, fwb + (size_t)l * (EMB * EMB), fb + l * EMB, bufB);
    float* ln2_dst = (it == 12) ? (float*)d_out : bufA;
    ln_kernel<<<BS_TOK, 256, 0, stream>>>(bufC, bufB, g2 + l * EMB, b2 + l * EMB,
                                          ln2_dst, XbA);
  }
}